// Round 2
// baseline (3758.079 us; speedup 1.0000x reference)
//
#include <hip/hip_runtime.h>
#include <math.h>

// ---------------------------------------------------------------------------
// SetAbstraction (PointNet++-style) for MI355X.
// Adaptive-workspace pipeline:
//   knnfps : fused KNN (256 blocks) + FPS (8 blocks)
//   k1     : per-point projections Q,R  (layer-1 folded: h1 = Q[n] + R[idx])
//   k2     : BN1 partials -> reduce
//   k3<S>  : e1=relu(bn1(h1)); h2=e1@w2+b2; BN2 partials; store h2 iff S
//   k4<R,T>: e2 tile (load h2 or recompute); t=e2@wa1+ba1; BNa partials; store t iff T
//   k5<R,T>: e2 tile; a=softmax_K(relu(bna(t))@wa2+ba2); out=sum_k a*e2
//   k6     : gather out[fps], BNf partials
//   k7     : write new_xyz + normalized nf in [B,COUT,NPOINT]
// h2 (268MB) and t (67MB) are only used if ws_size permits.
// ---------------------------------------------------------------------------

#define BB 8
#define NN 4096
#define CIN 64
#define CO 128
#define KNb 16
#define NP 1024

__device__ __forceinline__ float4 bnrelu4(float4 v, float4 s, float4 h) {
  float4 e;
  e.x = fmaxf(0.f, fmaf(v.x, s.x, h.x));
  e.y = fmaxf(0.f, fmaf(v.y, s.y, h.y));
  e.z = fmaxf(0.f, fmaf(v.z, s.z, h.z));
  e.w = fmaxf(0.f, fmaf(v.w, s.w, h.w));
  return e;
}

// ------------------------------------------------- fused KNN + FPS ----------
__global__ __launch_bounds__(256) void knnfps_kernel(const float* __restrict__ xyz,
                                                     int* __restrict__ idx,
                                                     int* __restrict__ fps) {
  __shared__ float smem[12304];
  const int blk = blockIdx.x;
  const int tid = threadIdx.x;
  if (blk < 256) {
    // ---- KNN: 128 rows/block, 2 threads per row (half the candidates each) --
    float4* cand = (float4*)smem;        // 1024 float4 = floats [0,4096)
    float* mdist = smem + 4096;          // 128*32 floats [4096,8192)
    int* midx = (int*)(smem + 8192);     // 128*32 ints   [8192,12288)
    const int b = blk >> 5;
    const int n0 = (blk & 31) << 7;
    const float* xb = xyz + b * 3 * NN;
    const int r = tid >> 1, h = tid & 1;
    const int n = n0 + r;
    const float xn = xb[n], yn = xb[NN + n], zn = xb[2 * NN + n];
    const float sqn = __fadd_rn(__fadd_rn(__fmul_rn(xn, xn), __fmul_rn(yn, yn)),
                                __fmul_rn(zn, zn));
    float bd[16];
    int bi[16];
#pragma unroll
    for (int j = 0; j < 16; ++j) { bd[j] = 3.4e38f; bi[j] = 0; }
    for (int ch = 0; ch < 4; ++ch) {
#pragma unroll
      for (int i = 0; i < 4; ++i) {
        int mm = i * 256 + tid;
        int m = (mm >> 9) * 2048 + ch * 512 + (mm & 511);
        float x = xb[m], y = xb[NN + m], z = xb[2 * NN + m];
        float sq = __fadd_rn(__fadd_rn(__fmul_rn(x, x), __fmul_rn(y, y)),
                             __fmul_rn(z, z));
        cand[mm] = make_float4(x, y, z, sq);
      }
      __syncthreads();
      const int base = h * 512;
      const int mbase = h * 2048 + ch * 512;
      for (int mm = 0; mm < 512; ++mm) {
        float4 pm = cand[base + mm];
        float dot = fmaf(zn, pm.z, fmaf(yn, pm.y, __fmul_rn(xn, pm.x)));
        float d = __fsub_rn(__fadd_rn(sqn, pm.w), __fmul_rn(2.0f, dot));
        if (d < bd[15]) {  // strict <: equal dist keeps earlier (lower) index
          float cd = d;
          int ci = mbase + mm;
#pragma unroll
          for (int j = 0; j < 16; ++j) {
            if (cd < bd[j]) {
              float tf = bd[j]; bd[j] = cd; cd = tf;
              int ti = bi[j]; bi[j] = ci; ci = ti;
            }
          }
        }
      }
      __syncthreads();
    }
#pragma unroll
    for (int j = 0; j < 16; ++j) {
      mdist[r * 32 + h * 16 + j] = bd[j];
      midx[r * 32 + h * 16 + j] = bi[j];
    }
    __syncthreads();
    if (tid < 128) {
      // merge two sorted 16-lists; all half-0 indices < half-1 -> ties take 0
      const float* d0 = mdist + tid * 32;
      const int* i0p = midx + tid * 32;
      int i = 0, j = 0;
      int* op = idx + (b * NN + n0 + tid) * KNb;
#pragma unroll
      for (int o = 0; o < 16; ++o) {  // i+j==o<=15 -> both pointers in range
        if (d0[i] <= d0[16 + j]) { op[o] = i0p[i]; ++i; }
        else { op[o] = i0p[16 + j]; ++j; }
      }
    }
  } else {
    // ---- FPS: one block per batch ----
    float* lx = smem;
    float* ly = smem + 4096;
    float* lz = smem + 8192;
    float* rd = smem + 12288;
    int* ri = (int*)(smem + 12292);
    const int b = blk - 256;
    const float* xb = xyz + b * 3 * NN;
    float px[16], py[16], pz[16], dist[16];
#pragma unroll
    for (int i = 0; i < 16; ++i) {
      int p = i * 256 + tid;
      float x = xb[p], y = xb[NN + p], z = xb[2 * NN + p];
      px[i] = x; py[i] = y; pz[i] = z; dist[i] = 1e10f;
      lx[p] = x; ly[p] = y; lz[p] = z;
    }
    if (tid == 0) fps[b * NP] = 0;
    __syncthreads();
    int far = 0;
    for (int s = 1; s < NP; ++s) {
      const float cx = lx[far], cy = ly[far], cz = lz[far];
      float bm = -1.0f;
      int bip = 0;
#pragma unroll
      for (int i = 0; i < 16; ++i) {
        float dx = __fsub_rn(px[i], cx);
        float dy = __fsub_rn(py[i], cy);
        float dz = __fsub_rn(pz[i], cz);
        float d = __fadd_rn(__fadd_rn(__fmul_rn(dx, dx), __fmul_rn(dy, dy)),
                            __fmul_rn(dz, dz));
        float nd = fminf(dist[i], d);
        dist[i] = nd;
        if (nd > bm) { bm = nd; bip = i * 256 + tid; }
      }
#pragma unroll
      for (int off = 1; off < 64; off <<= 1) {
        float od = __shfl_xor(bm, off);
        int oi = __shfl_xor(bip, off);
        if (od > bm || (od == bm && oi < bip)) { bm = od; bip = oi; }
      }
      if ((tid & 63) == 0) { rd[tid >> 6] = bm; ri[tid >> 6] = bip; }
      __syncthreads();
      float b0 = rd[0];
      int i0 = ri[0];
#pragma unroll
      for (int w = 1; w < 4; ++w) {
        float bw = rd[w]; int iw = ri[w];
        if (bw > b0 || (bw == b0 && iw < i0)) { b0 = bw; i0 = iw; }
      }
      far = i0;
      if (tid == 0) fps[b * NP + s] = far;
      __syncthreads();
    }
  }
}

// ------------------------------------------------- K1: Q,R projections ------
__global__ __launch_bounds__(256) void k1_proj(const float* __restrict__ feat,
                                               const float* __restrict__ xyz,
                                               const float* __restrict__ w1,
                                               const float* __restrict__ b1,
                                               float* __restrict__ Q,
                                               float* __restrict__ R) {
  __shared__ float sf[64][65];
  const int blk = blockIdx.x;
  const int b = blk >> 6;
  const int n0 = (blk & 63) << 6;
  const int tid = threadIdx.x;
#pragma unroll
  for (int i = 0; i < 16; ++i) {
    int lin = i * 256 + tid;
    int c = lin >> 6, nn2 = lin & 63;
    sf[c][nn2] = feat[(b * CIN + c) * NN + n0 + nn2];
  }
  __syncthreads();
  const int n = tid & 63;
  const int col0 = (tid >> 6) * 32;
  float qa[32], ra[32];
#pragma unroll
  for (int j = 0; j < 32; ++j) { qa[j] = 0.f; ra[j] = 0.f; }
  for (int c = 0; c < CIN; ++c) {
    float f = sf[c][n];
    const float4* wq = (const float4*)(w1 + c * CO + col0);
    const float4* wr = (const float4*)(w1 + (CIN + c) * CO + col0);
#pragma unroll
    for (int j = 0; j < 8; ++j) {
      float4 a = wq[j];
      float4 bb = wr[j];
      qa[4 * j + 0] = fmaf(f, a.x, qa[4 * j + 0]);
      qa[4 * j + 1] = fmaf(f, a.y, qa[4 * j + 1]);
      qa[4 * j + 2] = fmaf(f, a.z, qa[4 * j + 2]);
      qa[4 * j + 3] = fmaf(f, a.w, qa[4 * j + 3]);
      ra[4 * j + 0] = fmaf(f, bb.x, ra[4 * j + 0]);
      ra[4 * j + 1] = fmaf(f, bb.y, ra[4 * j + 1]);
      ra[4 * j + 2] = fmaf(f, bb.z, ra[4 * j + 2]);
      ra[4 * j + 3] = fmaf(f, bb.w, ra[4 * j + 3]);
    }
  }
  const float* xb = xyz + b * 3 * NN;
  const float xx = xb[n0 + n], yy = xb[NN + n0 + n], zz = xb[2 * NN + n0 + n];
#pragma unroll
  for (int j = 0; j < 32; ++j) {
    int col = col0 + j;
    float xp = fmaf(zz, w1[130 * CO + col],
                    fmaf(yy, w1[129 * CO + col], __fmul_rn(xx, w1[128 * CO + col])));
    qa[j] = qa[j] - xp + b1[col];
    ra[j] = ra[j] + xp;
  }
  float* qp = Q + (size_t)(b * NN + n0 + n) * CO + col0;
  float* rp = R + (size_t)(b * NN + n0 + n) * CO + col0;
#pragma unroll
  for (int j = 0; j < 8; ++j) {
    ((float4*)qp)[j] = make_float4(qa[4 * j], qa[4 * j + 1], qa[4 * j + 2], qa[4 * j + 3]);
    ((float4*)rp)[j] = make_float4(ra[4 * j], ra[4 * j + 1], ra[4 * j + 2], ra[4 * j + 3]);
  }
}

// ------------------------------------------------- K2: BN1 stats ------------
__global__ __launch_bounds__(256) void k2_stats1(const float* __restrict__ Q,
                                                 const float* __restrict__ R,
                                                 const int* __restrict__ idx,
                                                 float* __restrict__ part1) {
  __shared__ float red[512];
  const int blk = blockIdx.x;
  const int b = blk >> 6;
  const int n0 = (blk & 63) << 6;
  const int tid = threadIdx.x;
  const int c = tid & 127;
  const int sub = tid >> 7;
  float s = 0.f, q = 0.f;
  for (int nn2 = 0; nn2 < 32; ++nn2) {
    int n = n0 + sub * 32 + nn2;
    float qv = Q[(size_t)(b * NN + n) * CO + c];
    const int* ip = idx + (b * NN + n) * KNb;
#pragma unroll
    for (int k = 0; k < KNb; ++k) {
      int m = ip[k];
      float v = qv + R[(size_t)(b * NN + m) * CO + c];
      s += v;
      q = fmaf(v, v, q);
    }
  }
  red[tid] = s;
  __syncthreads();
  float qsave = q;
  if (tid < 128) part1[blk * 256 + tid] = red[tid] + red[tid + 128];
  __syncthreads();
  red[tid] = qsave;
  __syncthreads();
  if (tid < 128) part1[blk * 256 + 128 + tid] = red[tid] + red[tid + 128];
}

// ------------------------------------------------- stats reduce -------------
template <int C>
__global__ void reduce_stats_t(const float* __restrict__ part, int nblk,
                               const float* __restrict__ gamma,
                               const float* __restrict__ beta, float cnt,
                               float* __restrict__ scale, float* __restrict__ shift) {
  __shared__ double redS[8 * C];
  __shared__ double redQ[8 * C];
  const int tid = threadIdx.x;
  const int c = tid % C;
  const int sub = tid / C;
  double s = 0.0, q = 0.0;
  for (int i = sub; i < nblk; i += 8) {
    s += (double)part[i * 2 * C + c];
    q += (double)part[i * 2 * C + C + c];
  }
  redS[sub * C + c] = s;
  redQ[sub * C + c] = q;
  __syncthreads();
  if (tid < C) {
    double ss = 0.0, qq = 0.0;
#pragma unroll
    for (int k = 0; k < 8; ++k) { ss += redS[k * C + tid]; qq += redQ[k * C + tid]; }
    double mean = ss / (double)cnt;
    double var = qq / (double)cnt - mean * mean;
    float inv = 1.0f / sqrtf((float)var + 1e-5f);
    float sc = gamma[tid] * inv;
    scale[tid] = sc;
    shift[tid] = fmaf(-(float)mean, sc, beta[tid]);
  }
}

// ------------------------------------------------- K3: layer2 GEMM ----------
template <bool STOREH2>
__global__ __launch_bounds__(256) void k3_mm2(const float* __restrict__ Q,
                                              const float* __restrict__ R,
                                              const int* __restrict__ idx,
                                              const float* __restrict__ w2,
                                              const float* __restrict__ b2,
                                              const float* __restrict__ stats,
                                              float* __restrict__ h2,
                                              float* __restrict__ part2) {
  __shared__ float sE[64 * 132];
  const int blk = blockIdx.x;
  const int b = blk >> 10;
  const int n0 = (blk & 1023) * 4;
  const int rowbase = blk * 64;
  const int tid = threadIdx.x;
  const float* scale1 = stats;
  const float* shift1 = stats + 128;
  {
    const int r = tid >> 2, c0 = (tid & 3) * 32;
    const int np2 = r >> 4, k = r & 15;
    const int n = n0 + np2;
    const int m = idx[(b * NN + n) * KNb + k];
    const float4* qp = (const float4*)(Q + (size_t)(b * NN + n) * CO + c0);
    const float4* rp = (const float4*)(R + (size_t)(b * NN + m) * CO + c0);
    const float4* s4p = (const float4*)(scale1 + c0);
    const float4* h4p = (const float4*)(shift1 + c0);
    float* se = sE + r * 132 + c0;
#pragma unroll
    for (int j = 0; j < 8; ++j) {
      float4 a = qp[j];
      float4 bb = rp[j];
      float4 v = make_float4(a.x + bb.x, a.y + bb.y, a.z + bb.z, a.w + bb.w);
      ((float4*)se)[j] = bnrelu4(v, s4p[j], h4p[j]);
    }
  }
  __syncthreads();
  const int g = tid & 15;
  const int col0 = (tid >> 4) * 8;
  float acc[4][8];
#pragma unroll
  for (int i = 0; i < 4; ++i)
#pragma unroll
    for (int j = 0; j < 8; ++j) acc[i][j] = 0.f;
#pragma unroll 2
  for (int c = 0; c < CO; ++c) {
    float ev[4];
    ev[0] = sE[g * 132 + c];
    ev[1] = sE[(g + 16) * 132 + c];
    ev[2] = sE[(g + 32) * 132 + c];
    ev[3] = sE[(g + 48) * 132 + c];
    const float4 wa = *(const float4*)(w2 + c * CO + col0);
    const float4 wb = *(const float4*)(w2 + c * CO + col0 + 4);
    const float wv[8] = {wa.x, wa.y, wa.z, wa.w, wb.x, wb.y, wb.z, wb.w};
#pragma unroll
    for (int i = 0; i < 4; ++i)
#pragma unroll
      for (int j = 0; j < 8; ++j) acc[i][j] = fmaf(ev[i], wv[j], acc[i][j]);
  }
  const float4 bA = *(const float4*)(b2 + col0);
  const float4 bB = *(const float4*)(b2 + col0 + 4);
  const float bv[8] = {bA.x, bA.y, bA.z, bA.w, bB.x, bB.y, bB.z, bB.w};
  float bsum[8], bsq[8];
#pragma unroll
  for (int j = 0; j < 8; ++j) { bsum[j] = 0.f; bsq[j] = 0.f; }
#pragma unroll
  for (int i = 0; i < 4; ++i) {
    float v[8];
#pragma unroll
    for (int j = 0; j < 8; ++j) {
      v[j] = acc[i][j] + bv[j];
      bsum[j] += v[j];
      bsq[j] = fmaf(v[j], v[j], bsq[j]);
    }
    if constexpr (STOREH2) {
      float* hp = h2 + (size_t)(rowbase + g + 16 * i) * CO + col0;
      *(float4*)(hp) = make_float4(v[0], v[1], v[2], v[3]);
      *(float4*)(hp + 4) = make_float4(v[4], v[5], v[6], v[7]);
    }
  }
  __syncthreads();
  float* sS = sE;
  float* sQ2 = sE + 2048;
#pragma unroll
  for (int j = 0; j < 8; ++j) {
    sS[g * 128 + col0 + j] = bsum[j];
    sQ2[g * 128 + col0 + j] = bsq[j];
  }
  __syncthreads();
  if (tid < 128) {
    float ss = 0.f, qq = 0.f;
#pragma unroll
    for (int gg = 0; gg < 16; ++gg) {
      ss += sS[gg * 128 + tid];
      qq += sQ2[gg * 128 + tid];
    }
    part2[blk * 256 + tid] = ss;
    part2[blk * 256 + 128 + tid] = qq;
  }
}

// ------------------------------------------------- e2 tile builder ----------
template <bool RECOMP>
__device__ __forceinline__ void build_e2_tile(
    float* sE, const int b, const int n0, const int rowbase, const int tid,
    const float* __restrict__ Q, const float* __restrict__ R,
    const int* __restrict__ idx, const float* __restrict__ w2,
    const float* __restrict__ b2, const float* __restrict__ h2,
    const float* __restrict__ stats) {
  const float* sc2 = stats + 256;
  const float* sh2 = stats + 384;
  const int r = tid >> 2, c0 = (tid & 3) * 32;
  if constexpr (!RECOMP) {
    const float4* hp = (const float4*)(h2 + (size_t)(rowbase + r) * CO + c0);
    const float4* s4p = (const float4*)(sc2 + c0);
    const float4* h4p = (const float4*)(sh2 + c0);
    float* se = sE + r * 132 + c0;
#pragma unroll
    for (int j = 0; j < 8; ++j) ((float4*)se)[j] = bnrelu4(hp[j], s4p[j], h4p[j]);
    __syncthreads();
  } else {
    const float* sc1 = stats;
    const float* sh1 = stats + 128;
    {
      const int np2 = r >> 4, k = r & 15;
      const int n = n0 + np2;
      const int m = idx[(b * NN + n) * KNb + k];
      const float4* qp = (const float4*)(Q + (size_t)(b * NN + n) * CO + c0);
      const float4* rp = (const float4*)(R + (size_t)(b * NN + m) * CO + c0);
      const float4* s4p = (const float4*)(sc1 + c0);
      const float4* h4p = (const float4*)(sh1 + c0);
      float* se = sE + r * 132 + c0;
#pragma unroll
      for (int j = 0; j < 8; ++j) {
        float4 a = qp[j];
        float4 bb = rp[j];
        float4 v = make_float4(a.x + bb.x, a.y + bb.y, a.z + bb.z, a.w + bb.w);
        ((float4*)se)[j] = bnrelu4(v, s4p[j], h4p[j]);
      }
    }
    __syncthreads();
    const int g = tid & 15, col0 = (tid >> 4) * 8;
    float acc[4][8];
#pragma unroll
    for (int i = 0; i < 4; ++i)
#pragma unroll
      for (int j = 0; j < 8; ++j) acc[i][j] = 0.f;
#pragma unroll 2
    for (int c = 0; c < CO; ++c) {
      float ev[4];
      ev[0] = sE[g * 132 + c];
      ev[1] = sE[(g + 16) * 132 + c];
      ev[2] = sE[(g + 32) * 132 + c];
      ev[3] = sE[(g + 48) * 132 + c];
      const float4 wa = *(const float4*)(w2 + c * CO + col0);
      const float4 wb = *(const float4*)(w2 + c * CO + col0 + 4);
      const float wv[8] = {wa.x, wa.y, wa.z, wa.w, wb.x, wb.y, wb.z, wb.w};
#pragma unroll
      for (int i = 0; i < 4; ++i)
#pragma unroll
        for (int j = 0; j < 8; ++j) acc[i][j] = fmaf(ev[i], wv[j], acc[i][j]);
    }
    __syncthreads();  // all reads of e1 done before overwrite
    const float4 bA = *(const float4*)(b2 + col0);
    const float4 bB = *(const float4*)(b2 + col0 + 4);
    const float4 sA4 = *(const float4*)(sc2 + col0);
    const float4 sB4 = *(const float4*)(sc2 + col0 + 4);
    const float4 hA4 = *(const float4*)(sh2 + col0);
    const float4 hB4 = *(const float4*)(sh2 + col0 + 4);
#pragma unroll
    for (int i = 0; i < 4; ++i) {
      float4 v0 = make_float4(acc[i][0] + bA.x, acc[i][1] + bA.y,
                              acc[i][2] + bA.z, acc[i][3] + bA.w);
      float4 v1 = make_float4(acc[i][4] + bB.x, acc[i][5] + bB.y,
                              acc[i][6] + bB.z, acc[i][7] + bB.w);
      float* se = sE + (g + 16 * i) * 132 + col0;
      *(float4*)se = bnrelu4(v0, sA4, hA4);
      *(float4*)(se + 4) = bnrelu4(v1, sB4, hB4);
    }
    __syncthreads();
  }
}

// ------------------------------------------------- K4: attention MLP1 -------
template <bool RECOMP, bool STORET>
__global__ __launch_bounds__(256) void k4_attn1(
    const float* __restrict__ Q, const float* __restrict__ R,
    const int* __restrict__ idx, const float* __restrict__ w2,
    const float* __restrict__ b2, const float* __restrict__ h2,
    const float* __restrict__ wa1, const float* __restrict__ ba1,
    const float* __restrict__ stats, float* __restrict__ t,
    float* __restrict__ parta) {
  __shared__ float sE[64 * 132];
  const int blk = blockIdx.x;
  const int tid = threadIdx.x;
  const int b = blk >> 10;
  const int n0 = (blk & 1023) * 4;
  const int rowbase = blk * 64;
  build_e2_tile<RECOMP>(sE, b, n0, rowbase, tid, Q, R, idx, w2, b2, h2, stats);
  const int g = tid & 15;
  const int col0 = (tid >> 4) * 2;
  float a0 = 0.f, a1 = 0.f, a2 = 0.f, a3 = 0.f, b0 = 0.f, b1v = 0.f, b2v = 0.f, b3 = 0.f;
#pragma unroll 4
  for (int c = 0; c < CO; ++c) {
    float e0 = sE[g * 132 + c];
    float e1 = sE[(g + 16) * 132 + c];
    float e2 = sE[(g + 32) * 132 + c];
    float e3 = sE[(g + 48) * 132 + c];
    float2 w = *(const float2*)(wa1 + c * 32 + col0);
    a0 = fmaf(e0, w.x, a0); b0 = fmaf(e0, w.y, b0);
    a1 = fmaf(e1, w.x, a1); b1v = fmaf(e1, w.y, b1v);
    a2 = fmaf(e2, w.x, a2); b2v = fmaf(e2, w.y, b2v);
    a3 = fmaf(e3, w.x, a3); b3 = fmaf(e3, w.y, b3);
  }
  const float2 bb = *(const float2*)(ba1 + col0);
  float s2[2] = {0.f, 0.f}, q2[2] = {0.f, 0.f};
  float va[4] = {a0 + bb.x, a1 + bb.x, a2 + bb.x, a3 + bb.x};
  float vb[4] = {b0 + bb.y, b1v + bb.y, b2v + bb.y, b3 + bb.y};
#pragma unroll
  for (int i = 0; i < 4; ++i) {
    if constexpr (STORET) {
      *(float2*)(t + (size_t)(rowbase + g + 16 * i) * 32 + col0) = make_float2(va[i], vb[i]);
    }
    s2[0] += va[i]; q2[0] = fmaf(va[i], va[i], q2[0]);
    s2[1] += vb[i]; q2[1] = fmaf(vb[i], vb[i], q2[1]);
  }
  __syncthreads();
  float* sS = sE;
  sS[g * 32 + col0] = s2[0];
  sS[g * 32 + col0 + 1] = s2[1];
  sS[512 + g * 32 + col0] = q2[0];
  sS[512 + g * 32 + col0 + 1] = q2[1];
  __syncthreads();
  if (tid < 32) {
    float ss = 0.f, qq = 0.f;
#pragma unroll
    for (int gg = 0; gg < 16; ++gg) {
      ss += sS[gg * 32 + tid];
      qq += sS[512 + gg * 32 + tid];
    }
    parta[blk * 64 + tid] = ss;
    parta[blk * 64 + 32 + tid] = qq;
  }
}

// ------------------------------------------------- K5: softmax + out --------
template <bool RECOMP, bool LOADT>
__global__ __launch_bounds__(256) void k5_out(
    const float* __restrict__ Q, const float* __restrict__ R,
    const int* __restrict__ idx, const float* __restrict__ w2,
    const float* __restrict__ b2, const float* __restrict__ h2,
    const float* __restrict__ t, const float* __restrict__ wa1,
    const float* __restrict__ ba1, const float* __restrict__ wa2,
    const float* __restrict__ ba2, const float* __restrict__ stats,
    float* __restrict__ out) {
  __shared__ float sE[64 * 132];
  __shared__ float sA[64];
  const int blk = blockIdx.x;
  const int tid = threadIdx.x;
  const int b = blk >> 10;
  const int n0 = (blk & 1023) * 4;
  const int rowbase = blk * 64;
  build_e2_tile<RECOMP>(sE, b, n0, rowbase, tid, Q, R, idx, w2, b2, h2, stats);
  const float* sna = stats + 512;
  const float* sha = stats + 544;
  {
    const int r = tid >> 2, q = tid & 3;
    float a2 = 0.f;
    if constexpr (LOADT) {
      const float* tp = t + (size_t)(rowbase + r) * 32 + q * 8;
#pragma unroll
      for (int j = 0; j < 8; j += 4) {
        float4 tv = *(const float4*)(tp + j);
        float4 s4 = *(const float4*)(sna + q * 8 + j);
        float4 h4 = *(const float4*)(sha + q * 8 + j);
        a2 = fmaf(fmaxf(0.f, fmaf(tv.x, s4.x, h4.x)), wa2[q * 8 + j], a2);
        a2 = fmaf(fmaxf(0.f, fmaf(tv.y, s4.y, h4.y)), wa2[q * 8 + j + 1], a2);
        a2 = fmaf(fmaxf(0.f, fmaf(tv.z, s4.z, h4.z)), wa2[q * 8 + j + 2], a2);
        a2 = fmaf(fmaxf(0.f, fmaf(tv.w, s4.w, h4.w)), wa2[q * 8 + j + 3], a2);
      }
    } else {
      float tj[8];
      const float4 bA = *(const float4*)(ba1 + q * 8);
      const float4 bB = *(const float4*)(ba1 + q * 8 + 4);
      tj[0] = bA.x; tj[1] = bA.y; tj[2] = bA.z; tj[3] = bA.w;
      tj[4] = bB.x; tj[5] = bB.y; tj[6] = bB.z; tj[7] = bB.w;
      for (int c = 0; c < CO; ++c) {
        float e = sE[r * 132 + c];
        const float4 wA = *(const float4*)(wa1 + c * 32 + q * 8);
        const float4 wB = *(const float4*)(wa1 + c * 32 + q * 8 + 4);
        tj[0] = fmaf(e, wA.x, tj[0]); tj[1] = fmaf(e, wA.y, tj[1]);
        tj[2] = fmaf(e, wA.z, tj[2]); tj[3] = fmaf(e, wA.w, tj[3]);
        tj[4] = fmaf(e, wB.x, tj[4]); tj[5] = fmaf(e, wB.y, tj[5]);
        tj[6] = fmaf(e, wB.z, tj[6]); tj[7] = fmaf(e, wB.w, tj[7]);
      }
#pragma unroll
      for (int j = 0; j < 8; ++j)
        a2 = fmaf(fmaxf(0.f, fmaf(tj[j], sna[q * 8 + j], sha[q * 8 + j])),
                  wa2[q * 8 + j], a2);
    }
    a2 += __shfl_xor(a2, 1);
    a2 += __shfl_xor(a2, 2);
    a2 += ba2[0];
    float m = a2;
#pragma unroll
    for (int off = 4; off < 64; off <<= 1) m = fmaxf(m, __shfl_xor(m, off));
    float p = expf(a2 - m);
    float s = p;
#pragma unroll
    for (int off = 4; off < 64; off <<= 1) s += __shfl_xor(s, off);
    if (q == 0) sA[r] = p / s;
  }
  __syncthreads();
  const int np2 = tid >> 6;
  const int cg = tid & 63;
  const int c0 = cg * 2;
  float o0 = 0.f, o1 = 0.f;
#pragma unroll
  for (int k = 0; k < 16; ++k) {
    float aw = sA[np2 * 16 + k];
    o0 = fmaf(aw, sE[(np2 * 16 + k) * 132 + c0], o0);
    o1 = fmaf(aw, sE[(np2 * 16 + k) * 132 + c0 + 1], o1);
  }
  float* op = out + (size_t)(b * NN + n0 + np2) * CO + c0;
  *(float2*)op = make_float2(o0, o1);
}

// ------------------------------------------------- K6: gather stats ---------
__global__ __launch_bounds__(256) void k6_gstats(const float* __restrict__ out,
                                                 const int* __restrict__ fps,
                                                 float* __restrict__ partf) {
  __shared__ float red[512];
  const int blk = blockIdx.x;
  const int tid = threadIdx.x;
  const int c = tid & 127;
  const int half = tid >> 7;
  float s = 0.f, q = 0.f;
  for (int i = 0; i < 128; ++i) {
    int row = blk * 256 + half * 128 + i;
    int b = row >> 10, p = row & 1023;
    int fi = fps[b * NP + p];
    float v = out[(size_t)(b * NN + fi) * CO + c];
    s += v;
    q = fmaf(v, v, q);
  }
  red[tid] = s;
  red[256 + tid] = q;
  __syncthreads();
  if (tid < 128) {
    partf[blk * 256 + tid] = red[tid] + red[tid + 128];
    partf[blk * 256 + 128 + tid] = red[256 + tid] + red[256 + tid + 128];
  }
}

// ------------------------------------------------- K7: final outputs --------
__global__ __launch_bounds__(256) void k7_final(const float* __restrict__ xyz,
                                                const float* __restrict__ out,
                                                const int* __restrict__ fps,
                                                const float* __restrict__ stats,
                                                float* __restrict__ dout) {
  const int gid = blockIdx.x * 256 + threadIdx.x;
  const int NX = BB * 3 * NP;  // 24576
  if (gid < NX) {
    int b = gid / 3072;
    int rem = gid - b * 3072;
    int d = rem >> 10, p = rem & 1023;
    int fi = fps[b * NP + p];
    dout[gid] = xyz[(b * 3 + d) * NN + fi];
  } else {
    int h = gid - NX;
    if (h < BB * CO * NP) {
      int b = h >> 17;
      int c = (h >> 10) & 127;
      int p = h & 1023;
      int fi = fps[b * NP + p];
      float v = out[(size_t)(b * NN + fi) * CO + c];
      dout[gid] = fmaf(v, stats[576 + c], stats[704 + c]);
    }
  }
}

// ---------------------------------------------------------------------------
extern "C" void kernel_launch(void* const* d_in, const int* in_sizes, int n_in,
                              void* d_out, int out_size, void* d_ws, size_t ws_size,
                              hipStream_t stream) {
  const float* xyz = (const float*)d_in[0];
  const float* feat = (const float*)d_in[1];
  const float* w1 = (const float*)d_in[2];
  const float* b1 = (const float*)d_in[3];
  const float* g1 = (const float*)d_in[4];
  const float* be1 = (const float*)d_in[5];
  const float* w2 = (const float*)d_in[6];
  const float* b2 = (const float*)d_in[7];
  const float* g2 = (const float*)d_in[8];
  const float* be2 = (const float*)d_in[9];
  const float* wa1 = (const float*)d_in[10];
  const float* ba1 = (const float*)d_in[11];
  const float* ga = (const float*)d_in[12];
  const float* bea = (const float*)d_in[13];
  const float* wa2 = (const float*)d_in[14];
  const float* ba2 = (const float*)d_in[15];
  const float* gf = (const float*)d_in[16];
  const float* bf = (const float*)d_in[17];
  float* outp = (float*)d_out;

  char* ws = (char*)d_ws;
  size_t off = 0;
  auto alloc = [&](size_t bytes) -> void* {
    void* p = ws + off;
    off = (off + bytes + 255) & ~(size_t)255;
    return p;
  };
  int* idx = (int*)alloc((size_t)BB * NN * KNb * 4);
  int* fpsb = (int*)alloc((size_t)BB * NP * 4);
  float* Q = (float*)alloc((size_t)BB * NN * CO * 4);
  float* R = (float*)alloc((size_t)BB * NN * CO * 4);
  float* ob = (float*)alloc((size_t)BB * NN * CO * 4);
  float* part1 = (float*)alloc((size_t)512 * 256 * 4);
  float* part2 = (float*)alloc((size_t)8192 * 256 * 4);
  float* parta = (float*)alloc((size_t)8192 * 64 * 4);
  float* partf = (float*)alloc((size_t)32 * 256 * 4);
  float* stats = (float*)alloc((size_t)1024 * 4);
  // optional big buffers, in priority order (h2 saves 2 GEMM passes, t saves 1/4)
  const size_t h2_bytes = (size_t)BB * NN * KNb * CO * 4;  // 268 MB
  const size_t t_bytes = (size_t)BB * NN * KNb * 32 * 4;   // 67 MB
  const bool has_h2 = (off + h2_bytes + 256 <= ws_size);
  float* h2 = has_h2 ? (float*)alloc(h2_bytes) : nullptr;
  const bool has_t = (off + t_bytes + 256 <= ws_size);
  float* tb = has_t ? (float*)alloc(t_bytes) : nullptr;

  const float CNT1 = (float)(BB * NN * KNb);
  knnfps_kernel<<<264, 256, 0, stream>>>(xyz, idx, fpsb);
  k1_proj<<<512, 256, 0, stream>>>(feat, xyz, w1, b1, Q, R);
  k2_stats1<<<512, 256, 0, stream>>>(Q, R, idx, part1);
  reduce_stats_t<128><<<1, 1024, 0, stream>>>(part1, 512, g1, be1, CNT1, stats, stats + 128);
  if (has_h2)
    k3_mm2<true><<<8192, 256, 0, stream>>>(Q, R, idx, w2, b2, stats, h2, part2);
  else
    k3_mm2<false><<<8192, 256, 0, stream>>>(Q, R, idx, w2, b2, stats, h2, part2);
  reduce_stats_t<128><<<1, 1024, 0, stream>>>(part2, 8192, g2, be2, CNT1, stats + 256, stats + 384);
  if (has_h2 && has_t)
    k4_attn1<false, true><<<8192, 256, 0, stream>>>(Q, R, idx, w2, b2, h2, wa1, ba1, stats, tb, parta);
  else if (has_h2)
    k4_attn1<false, false><<<8192, 256, 0, stream>>>(Q, R, idx, w2, b2, h2, wa1, ba1, stats, tb, parta);
  else if (has_t)
    k4_attn1<true, true><<<8192, 256, 0, stream>>>(Q, R, idx, w2, b2, h2, wa1, ba1, stats, tb, parta);
  else
    k4_attn1<true, false><<<8192, 256, 0, stream>>>(Q, R, idx, w2, b2, h2, wa1, ba1, stats, tb, parta);
  reduce_stats_t<32><<<1, 256, 0, stream>>>(parta, 8192, ga, bea, CNT1, stats + 512, stats + 544);
  if (has_h2 && has_t)
    k5_out<false, true><<<8192, 256, 0, stream>>>(Q, R, idx, w2, b2, h2, tb, wa1, ba1, wa2, ba2, stats, ob);
  else if (has_h2)
    k5_out<false, false><<<8192, 256, 0, stream>>>(Q, R, idx, w2, b2, h2, tb, wa1, ba1, wa2, ba2, stats, ob);
  else if (has_t)
    k5_out<true, true><<<8192, 256, 0, stream>>>(Q, R, idx, w2, b2, h2, tb, wa1, ba1, wa2, ba2, stats, ob);
  else
    k5_out<true, false><<<8192, 256, 0, stream>>>(Q, R, idx, w2, b2, h2, tb, wa1, ba1, wa2, ba2, stats, ob);
  k6_gstats<<<32, 256, 0, stream>>>(ob, fpsb, partf);
  reduce_stats_t<128><<<1, 1024, 0, stream>>>(partf, 32, gf, bf, (float)(BB * NP), stats + 576, stats + 704);
  k7_final<<<4192, 256, 0, stream>>>(xyz, ob, fpsb, stats, outp);
}

// Round 3
// 2684.625 us; speedup vs baseline: 1.3999x; 1.3999x over previous
//
#include <hip/hip_runtime.h>
#include <math.h>

// ---------------------------------------------------------------------------
// SetAbstraction (PointNet++-style) for MI355X.
//   front : fps chunk (8 blk) + KNN partial top-16 (1024 blk) + k1 Q/R (512 blk)
//   k2m   : fps chunk + 8-way key merge -> idx + BN1 partials
//   k3    : fps chunk + e1=relu(bn1(h1)); h2=e1@w2+b2; BN2 partials
//   k4    : fps chunk + e2 tile; t=e2@wa1+ba1; BNa partials
//   k5    : fps chunk + softmax_K; out=sum_k a*e2
//   k6/k7 : gather stats + final outputs
// FPS is a 1023-step serial chain (~0.4-0.5us/iter) staged across launches.
// ---------------------------------------------------------------------------

#define BB 8
#define NN 4096
#define CIN 64
#define CO 128
#define KNb 16
#define NP 1024

__device__ __forceinline__ float4 bnrelu4(float4 v, float4 s, float4 h) {
  float4 e;
  e.x = fmaxf(0.f, fmaf(v.x, s.x, h.x));
  e.y = fmaxf(0.f, fmaf(v.y, s.y, h.y));
  e.z = fmaxf(0.f, fmaf(v.z, s.z, h.z));
  e.w = fmaxf(0.f, fmaf(v.w, s.w, h.w));
  return e;
}

// ---------------- DPP wave(64) reductions: result broadcast via readlane ----
__device__ __forceinline__ float wave_fmax_bcast(float x) {
#define DPPF(ctrl, rmask)                                                        \
  {                                                                              \
    int t_ = __builtin_amdgcn_update_dpp(0xff800000, __float_as_int(x), ctrl,    \
                                         rmask, 0xf, false);                     \
    x = fmaxf(x, __int_as_float(t_));                                            \
  }
  DPPF(0x111, 0xf) DPPF(0x112, 0xf) DPPF(0x114, 0xf) DPPF(0x118, 0xf)
  DPPF(0x142, 0xa) DPPF(0x143, 0xc)
#undef DPPF
  return __int_as_float(__builtin_amdgcn_readlane(__float_as_int(x), 63));
}
__device__ __forceinline__ unsigned wave_umin_bcast(unsigned x) {
#define DPPU(ctrl, rmask)                                                        \
  {                                                                              \
    unsigned t_ = (unsigned)__builtin_amdgcn_update_dpp(-1, (int)x, ctrl, rmask, \
                                                        0xf, false);             \
    x = (t_ < x) ? t_ : x;                                                       \
  }
  DPPU(0x111, 0xf) DPPU(0x112, 0xf) DPPU(0x114, 0xf) DPPU(0x118, 0xf)
  DPPU(0x142, 0xa) DPPU(0x143, 0xc)
#undef DPPU
  return (unsigned)__builtin_amdgcn_readlane((int)x, 63);
}

// ---------------- FPS chunk: iters [s0,s1), state in fdist / fps[] ----------
__device__ void fps_chunk(const float* __restrict__ xyz, float* __restrict__ fdist,
                          int* __restrict__ fpsb, float* slotF, int* slotP,
                          int b, int s0, int s1, int tid) {
  const float* xb = xyz + b * 3 * NN;
  float px[16], py[16], pz[16], dist[16];
#pragma unroll
  for (int i = 0; i < 16; ++i) {
    int p = i * 256 + tid;
    px[i] = xb[p]; py[i] = xb[NN + p]; pz[i] = xb[2 * NN + p];
  }
  int far;
  if (s0 == 1) {
#pragma unroll
    for (int i = 0; i < 16; ++i) dist[i] = 1e10f;
    far = 0;
    if (tid == 0) fpsb[b * NP] = 0;
  } else {
#pragma unroll
    for (int i = 0; i < 16; ++i) dist[i] = fdist[b * NN + i * 256 + tid];
    far = fpsb[b * NP + s0 - 1];
  }
  for (int s = s0; s < s1; ++s) {
    const float cx = xb[far], cy = xb[NN + far], cz = xb[2 * NN + far];
    float lm = -3.4e38f;
    int lp = 0x7FFFFFFF;
#pragma unroll
    for (int i = 0; i < 16; ++i) {
      float dx = __fsub_rn(px[i], cx);
      float dy = __fsub_rn(py[i], cy);
      float dz = __fsub_rn(pz[i], cz);
      float d = __fadd_rn(__fadd_rn(__fmul_rn(dx, dx), __fmul_rn(dy, dy)),
                          __fmul_rn(dz, dz));
      float nd = fminf(dist[i], d);
      dist[i] = nd;
      bool gt = nd > lm;  // strict >: earliest (lowest) index kept
      lm = gt ? nd : lm;
      lp = gt ? (i * 256 + tid) : lp;
    }
    float wm = wave_fmax_bcast(lm);
    unsigned cand = (lm == wm) ? (unsigned)lp : 0xFFFFFFFFu;
    unsigned wp = wave_umin_bcast(cand);
    const int w = tid >> 6, par = (s & 1) * 4;
    if ((tid & 63) == 0) { slotF[par + w] = wm; slotP[par + w] = (int)wp; }
    __syncthreads();
    float bf = slotF[par]; int bp = slotP[par];
#pragma unroll
    for (int w2 = 1; w2 < 4; ++w2) {
      float f = slotF[par + w2]; int p = slotP[par + w2];
      if (f > bf || (f == bf && p < bp)) { bf = f; bp = p; }
    }
    far = bp;
    if (tid == 0) fpsb[b * NP + s] = far;
  }
#pragma unroll
  for (int i = 0; i < 16; ++i) fdist[b * NN + i * 256 + tid] = dist[i];
}

// ---------------- front: fps(8) + knn partial(1024) + k1(512) ---------------
__global__ __launch_bounds__(256) void front_kernel(
    const float* __restrict__ xyz, const float* __restrict__ feat,
    const float* __restrict__ w1, const float* __restrict__ b1,
    unsigned long long* __restrict__ part, float* __restrict__ Q,
    float* __restrict__ R, float* __restrict__ fdist, int* __restrict__ fpsb) {
  __shared__ __align__(16) float smem[4224];
  const int blk = blockIdx.x;
  const int tid = threadIdx.x;
  if (blk < 8) {
    fps_chunk(xyz, fdist, fpsb, smem, (int*)(smem + 8), blk, 1, 401, tid);
  } else if (blk < 8 + 1024) {
    // ---- KNN partial: 256 rows/block, 512-candidate range, u64 keys ----
    const int blkk = blk - 8;
    const int b = blkk >> 7;
    const int rem = blkk & 127;
    const int n = (rem >> 3) * 256 + tid;  // row
    const int m0 = (rem & 7) * 512;        // candidate range start
    const float* xb = xyz + b * 3 * NN;
    float4* cand = (float4*)smem;
#pragma unroll
    for (int i = 0; i < 2; ++i) {
      int local = i * 256 + tid;
      int m = m0 + local;
      float x = xb[m], y = xb[NN + m], z = xb[2 * NN + m];
      float sq = __fadd_rn(__fadd_rn(__fmul_rn(x, x), __fmul_rn(y, y)),
                           __fmul_rn(z, z));
      cand[local] = make_float4(x, y, z, sq);
    }
    const float xn = xb[n], yn = xb[NN + n], zn = xb[2 * NN + n];
    const float sqn = __fadd_rn(__fadd_rn(__fmul_rn(xn, xn), __fmul_rn(yn, yn)),
                                __fmul_rn(zn, zn));
    unsigned long long bd[16];
#pragma unroll
    for (int j = 0; j < 16; ++j) bd[j] = ~0ull;
    __syncthreads();
    for (int mm = 0; mm < 512; ++mm) {
      float4 pm = cand[mm];
      float dot = fmaf(zn, pm.z, fmaf(yn, pm.y, __fmul_rn(xn, pm.x)));
      float d = __fsub_rn(__fadd_rn(sqn, pm.w), __fmul_rn(2.0f, dot));
      unsigned ub = __float_as_uint(d);
      unsigned su = (d >= 0.f) ? (ub | 0x80000000u) : ~ub;
      unsigned long long key = ((unsigned long long)su << 32) | (unsigned)(m0 + mm);
      if (key < bd[15]) {
        unsigned long long cur = key;
#pragma unroll
        for (int j = 0; j < 16; ++j) {
          bool lt = cur < bd[j];
          unsigned long long mn = lt ? cur : bd[j];
          cur = lt ? bd[j] : cur;
          bd[j] = mn;
        }
      }
    }
    unsigned long long* op = part + ((size_t)(b * NN + n)) * 128 + (rem & 7) * 16;
#pragma unroll
    for (int j = 0; j < 16; ++j) op[j] = bd[j];
  } else {
    // ---- k1: Q,R projections ----
    const int blkk = blk - (8 + 1024);
    const int b = blkk >> 6;
    const int n0 = (blkk & 63) << 6;
    float* sf = smem;  // [64][65]
#pragma unroll
    for (int i = 0; i < 16; ++i) {
      int lin = i * 256 + tid;
      int c = lin >> 6, nn2 = lin & 63;
      sf[c * 65 + nn2] = feat[(b * CIN + c) * NN + n0 + nn2];
    }
    __syncthreads();
    const int n = tid & 63;
    const int col0 = (tid >> 6) * 32;
    float qa[32], ra[32];
#pragma unroll
    for (int j = 0; j < 32; ++j) { qa[j] = 0.f; ra[j] = 0.f; }
    for (int c = 0; c < CIN; ++c) {
      float f = sf[c * 65 + n];
      const float4* wq = (const float4*)(w1 + c * CO + col0);
      const float4* wr = (const float4*)(w1 + (CIN + c) * CO + col0);
#pragma unroll
      for (int j = 0; j < 8; ++j) {
        float4 a = wq[j];
        float4 bb = wr[j];
        qa[4 * j + 0] = fmaf(f, a.x, qa[4 * j + 0]);
        qa[4 * j + 1] = fmaf(f, a.y, qa[4 * j + 1]);
        qa[4 * j + 2] = fmaf(f, a.z, qa[4 * j + 2]);
        qa[4 * j + 3] = fmaf(f, a.w, qa[4 * j + 3]);
        ra[4 * j + 0] = fmaf(f, bb.x, ra[4 * j + 0]);
        ra[4 * j + 1] = fmaf(f, bb.y, ra[4 * j + 1]);
        ra[4 * j + 2] = fmaf(f, bb.z, ra[4 * j + 2]);
        ra[4 * j + 3] = fmaf(f, bb.w, ra[4 * j + 3]);
      }
    }
    const float* xb = xyz + b * 3 * NN;
    const float xx = xb[n0 + n], yy = xb[NN + n0 + n], zz = xb[2 * NN + n0 + n];
#pragma unroll
    for (int j = 0; j < 32; ++j) {
      int col = col0 + j;
      float xp = fmaf(zz, w1[130 * CO + col],
                      fmaf(yy, w1[129 * CO + col], __fmul_rn(xx, w1[128 * CO + col])));
      qa[j] = qa[j] - xp + b1[col];
      ra[j] = ra[j] + xp;
    }
    float* qp = Q + (size_t)(b * NN + n0 + n) * CO + col0;
    float* rp = R + (size_t)(b * NN + n0 + n) * CO + col0;
#pragma unroll
    for (int j = 0; j < 8; ++j) {
      ((float4*)qp)[j] = make_float4(qa[4 * j], qa[4 * j + 1], qa[4 * j + 2], qa[4 * j + 3]);
      ((float4*)rp)[j] = make_float4(ra[4 * j], ra[4 * j + 1], ra[4 * j + 2], ra[4 * j + 3]);
    }
  }
}

// ---------------- k2m: fps(8) + merge->idx + BN1 partials -------------------
__global__ __launch_bounds__(256) void k2m_kernel(
    const float* __restrict__ xyz, const unsigned long long* __restrict__ part,
    const float* __restrict__ Q, const float* __restrict__ R,
    int* __restrict__ idx, float* __restrict__ part1, float* __restrict__ fdist,
    int* __restrict__ fpsb) {
  __shared__ int smIdx[1024];
  __shared__ float red[512];
  const int blk = blockIdx.x;
  const int tid = threadIdx.x;
  if (blk < 8) {
    fps_chunk(xyz, fdist, fpsb, red, (int*)(red + 8), blk, 401, 501, tid);
    return;
  }
  const int blkk = blk - 8;
  const int b = blkk >> 6;
  const int n0 = (blkk & 63) * 64;
  // phase A: 8-way merge of sorted 16-lists (u64 keys; ties impossible)
  if (tid < 64) {
    const int row = n0 + tid;
    const unsigned long long* lp = part + (size_t)(b * NN + row) * 128;
    int pos[8] = {0, 0, 0, 0, 0, 0, 0, 0};
    int* op = idx + (b * NN + row) * KNb;
#pragma unroll
    for (int o = 0; o < 16; ++o) {
      unsigned long long best = ~0ull;
      int bt = 0;
#pragma unroll
      for (int t = 0; t < 8; ++t) {
        unsigned long long h = (pos[t] < 16) ? lp[t * 16 + pos[t]] : ~0ull;
        if (h < best) { best = h; bt = t; }
      }
#pragma unroll
      for (int t = 0; t < 8; ++t) pos[t] += (t == bt) ? 1 : 0;
      int m = (int)(unsigned)(best & 0xFFFFFFFFull);
      smIdx[tid * 16 + o] = m;
      op[o] = m;
    }
  }
  __syncthreads();
  // phase B: BN1 stats over h1 = Q[n] + R[m]
  const int c = tid & 127;
  const int sub = tid >> 7;
  float s = 0.f, q = 0.f;
  for (int nn2 = 0; nn2 < 32; ++nn2) {
    int rl = sub * 32 + nn2;
    int n = n0 + rl;
    float qv = Q[(size_t)(b * NN + n) * CO + c];
#pragma unroll
    for (int k = 0; k < KNb; ++k) {
      int m = smIdx[rl * 16 + k];
      float v = qv + R[(size_t)(b * NN + m) * CO + c];
      s += v;
      q = fmaf(v, v, q);
    }
  }
  red[tid] = s;
  __syncthreads();
  float qsave = q;
  if (tid < 128) part1[blkk * 256 + tid] = red[tid] + red[tid + 128];
  __syncthreads();
  red[tid] = qsave;
  __syncthreads();
  if (tid < 128) part1[blkk * 256 + 128 + tid] = red[tid] + red[tid + 128];
}

// ------------------------------------------------- stats reduce -------------
template <int C>
__global__ void reduce_stats_t(const float* __restrict__ part, int nblk,
                               const float* __restrict__ gamma,
                               const float* __restrict__ beta, float cnt,
                               float* __restrict__ scale, float* __restrict__ shift) {
  __shared__ double redS[8 * C];
  __shared__ double redQ[8 * C];
  const int tid = threadIdx.x;
  const int c = tid % C;
  const int sub = tid / C;
  double s = 0.0, q = 0.0;
  for (int i = sub; i < nblk; i += 8) {
    s += (double)part[i * 2 * C + c];
    q += (double)part[i * 2 * C + C + c];
  }
  redS[sub * C + c] = s;
  redQ[sub * C + c] = q;
  __syncthreads();
  if (tid < C) {
    double ss = 0.0, qq = 0.0;
#pragma unroll
    for (int k = 0; k < 8; ++k) { ss += redS[k * C + tid]; qq += redQ[k * C + tid]; }
    double mean = ss / (double)cnt;
    double var = qq / (double)cnt - mean * mean;
    float inv = 1.0f / sqrtf((float)var + 1e-5f);
    float sc = gamma[tid] * inv;
    scale[tid] = sc;
    shift[tid] = fmaf(-(float)mean, sc, beta[tid]);
  }
}

// ------------------------------------------------- K3: layer2 GEMM ----------
template <bool STOREH2>
__global__ __launch_bounds__(256) void k3_mm2(const float* __restrict__ Q,
                                              const float* __restrict__ R,
                                              const int* __restrict__ idx,
                                              const float* __restrict__ w2,
                                              const float* __restrict__ b2,
                                              const float* __restrict__ stats,
                                              float* __restrict__ h2,
                                              float* __restrict__ part2,
                                              const float* __restrict__ xyz,
                                              float* __restrict__ fdist,
                                              int* __restrict__ fpsb) {
  __shared__ float sE[64 * 132];
  const int tid = threadIdx.x;
  if (blockIdx.x < 8) {
    fps_chunk(xyz, fdist, fpsb, sE, (int*)(sE + 8), blockIdx.x, 501, 801, tid);
    return;
  }
  const int blk = blockIdx.x - 8;
  const int b = blk >> 10;
  const int n0 = (blk & 1023) * 4;
  const int rowbase = blk * 64;
  const float* scale1 = stats;
  const float* shift1 = stats + 128;
  {
    const int r = tid >> 2, c0 = (tid & 3) * 32;
    const int np2 = r >> 4, k = r & 15;
    const int n = n0 + np2;
    const int m = idx[(b * NN + n) * KNb + k];
    const float4* qp = (const float4*)(Q + (size_t)(b * NN + n) * CO + c0);
    const float4* rp = (const float4*)(R + (size_t)(b * NN + m) * CO + c0);
    const float4* s4p = (const float4*)(scale1 + c0);
    const float4* h4p = (const float4*)(shift1 + c0);
    float* se = sE + r * 132 + c0;
#pragma unroll
    for (int j = 0; j < 8; ++j) {
      float4 a = qp[j];
      float4 bb = rp[j];
      float4 v = make_float4(a.x + bb.x, a.y + bb.y, a.z + bb.z, a.w + bb.w);
      ((float4*)se)[j] = bnrelu4(v, s4p[j], h4p[j]);
    }
  }
  __syncthreads();
  const int g = tid & 15;
  const int col0 = (tid >> 4) * 8;
  float acc[4][8];
#pragma unroll
  for (int i = 0; i < 4; ++i)
#pragma unroll
    for (int j = 0; j < 8; ++j) acc[i][j] = 0.f;
#pragma unroll 2
  for (int c = 0; c < CO; ++c) {
    float ev[4];
    ev[0] = sE[g * 132 + c];
    ev[1] = sE[(g + 16) * 132 + c];
    ev[2] = sE[(g + 32) * 132 + c];
    ev[3] = sE[(g + 48) * 132 + c];
    const float4 wa = *(const float4*)(w2 + c * CO + col0);
    const float4 wb = *(const float4*)(w2 + c * CO + col0 + 4);
    const float wv[8] = {wa.x, wa.y, wa.z, wa.w, wb.x, wb.y, wb.z, wb.w};
#pragma unroll
    for (int i = 0; i < 4; ++i)
#pragma unroll
      for (int j = 0; j < 8; ++j) acc[i][j] = fmaf(ev[i], wv[j], acc[i][j]);
  }
  const float4 bA = *(const float4*)(b2 + col0);
  const float4 bB = *(const float4*)(b2 + col0 + 4);
  const float bv[8] = {bA.x, bA.y, bA.z, bA.w, bB.x, bB.y, bB.z, bB.w};
  float bsum[8], bsq[8];
#pragma unroll
  for (int j = 0; j < 8; ++j) { bsum[j] = 0.f; bsq[j] = 0.f; }
#pragma unroll
  for (int i = 0; i < 4; ++i) {
    float v[8];
#pragma unroll
    for (int j = 0; j < 8; ++j) {
      v[j] = acc[i][j] + bv[j];
      bsum[j] += v[j];
      bsq[j] = fmaf(v[j], v[j], bsq[j]);
    }
    if constexpr (STOREH2) {
      float* hp = h2 + (size_t)(rowbase + g + 16 * i) * CO + col0;
      *(float4*)(hp) = make_float4(v[0], v[1], v[2], v[3]);
      *(float4*)(hp + 4) = make_float4(v[4], v[5], v[6], v[7]);
    }
  }
  __syncthreads();
  float* sS = sE;
  float* sQ2 = sE + 2048;
#pragma unroll
  for (int j = 0; j < 8; ++j) {
    sS[g * 128 + col0 + j] = bsum[j];
    sQ2[g * 128 + col0 + j] = bsq[j];
  }
  __syncthreads();
  if (tid < 128) {
    float ss = 0.f, qq = 0.f;
#pragma unroll
    for (int gg = 0; gg < 16; ++gg) {
      ss += sS[gg * 128 + tid];
      qq += sQ2[gg * 128 + tid];
    }
    part2[blk * 256 + tid] = ss;
    part2[blk * 256 + 128 + tid] = qq;
  }
}

// ------------------------------------------------- e2 tile builder ----------
template <bool RECOMP>
__device__ __forceinline__ void build_e2_tile(
    float* sE, const int b, const int n0, const int rowbase, const int tid,
    const float* __restrict__ Q, const float* __restrict__ R,
    const int* __restrict__ idx, const float* __restrict__ w2,
    const float* __restrict__ b2, const float* __restrict__ h2,
    const float* __restrict__ stats) {
  const float* sc2 = stats + 256;
  const float* sh2 = stats + 384;
  const int r = tid >> 2, c0 = (tid & 3) * 32;
  if constexpr (!RECOMP) {
    const float4* hp = (const float4*)(h2 + (size_t)(rowbase + r) * CO + c0);
    const float4* s4p = (const float4*)(sc2 + c0);
    const float4* h4p = (const float4*)(sh2 + c0);
    float* se = sE + r * 132 + c0;
#pragma unroll
    for (int j = 0; j < 8; ++j) ((float4*)se)[j] = bnrelu4(hp[j], s4p[j], h4p[j]);
    __syncthreads();
  } else {
    const float* sc1 = stats;
    const float* sh1 = stats + 128;
    {
      const int np2 = r >> 4, k = r & 15;
      const int n = n0 + np2;
      const int m = idx[(b * NN + n) * KNb + k];
      const float4* qp = (const float4*)(Q + (size_t)(b * NN + n) * CO + c0);
      const float4* rp = (const float4*)(R + (size_t)(b * NN + m) * CO + c0);
      const float4* s4p = (const float4*)(sc1 + c0);
      const float4* h4p = (const float4*)(sh1 + c0);
      float* se = sE + r * 132 + c0;
#pragma unroll
      for (int j = 0; j < 8; ++j) {
        float4 a = qp[j];
        float4 bb = rp[j];
        float4 v = make_float4(a.x + bb.x, a.y + bb.y, a.z + bb.z, a.w + bb.w);
        ((float4*)se)[j] = bnrelu4(v, s4p[j], h4p[j]);
      }
    }
    __syncthreads();
    const int g = tid & 15, col0 = (tid >> 4) * 8;
    float acc[4][8];
#pragma unroll
    for (int i = 0; i < 4; ++i)
#pragma unroll
      for (int j = 0; j < 8; ++j) acc[i][j] = 0.f;
#pragma unroll 2
    for (int c = 0; c < CO; ++c) {
      float ev[4];
      ev[0] = sE[g * 132 + c];
      ev[1] = sE[(g + 16) * 132 + c];
      ev[2] = sE[(g + 32) * 132 + c];
      ev[3] = sE[(g + 48) * 132 + c];
      const float4 wa = *(const float4*)(w2 + c * CO + col0);
      const float4 wb = *(const float4*)(w2 + c * CO + col0 + 4);
      const float wv[8] = {wa.x, wa.y, wa.z, wa.w, wb.x, wb.y, wb.z, wb.w};
#pragma unroll
      for (int i = 0; i < 4; ++i)
#pragma unroll
        for (int j = 0; j < 8; ++j) acc[i][j] = fmaf(ev[i], wv[j], acc[i][j]);
    }
    __syncthreads();  // all reads of e1 done before overwrite
    const float4 bA = *(const float4*)(b2 + col0);
    const float4 bB = *(const float4*)(b2 + col0 + 4);
    const float4 sA4 = *(const float4*)(sc2 + col0);
    const float4 sB4 = *(const float4*)(sc2 + col0 + 4);
    const float4 hA4 = *(const float4*)(sh2 + col0);
    const float4 hB4 = *(const float4*)(sh2 + col0 + 4);
#pragma unroll
    for (int i = 0; i < 4; ++i) {
      float4 v0 = make_float4(acc[i][0] + bA.x, acc[i][1] + bA.y,
                              acc[i][2] + bA.z, acc[i][3] + bA.w);
      float4 v1 = make_float4(acc[i][4] + bB.x, acc[i][5] + bB.y,
                              acc[i][6] + bB.z, acc[i][7] + bB.w);
      float* se = sE + (g + 16 * i) * 132 + col0;
      *(float4*)se = bnrelu4(v0, sA4, hA4);
      *(float4*)(se + 4) = bnrelu4(v1, sB4, hB4);
    }
    __syncthreads();
  }
}

// ------------------------------------------------- K4: attention MLP1 -------
template <bool RECOMP, bool STORET>
__global__ __launch_bounds__(256) void k4_attn1(
    const float* __restrict__ Q, const float* __restrict__ R,
    const int* __restrict__ idx, const float* __restrict__ w2,
    const float* __restrict__ b2, const float* __restrict__ h2,
    const float* __restrict__ wa1, const float* __restrict__ ba1,
    const float* __restrict__ stats, float* __restrict__ t,
    float* __restrict__ parta, const float* __restrict__ xyz,
    float* __restrict__ fdist, int* __restrict__ fpsb) {
  __shared__ float sE[64 * 132];
  const int tid = threadIdx.x;
  if (blockIdx.x < 8) {
    fps_chunk(xyz, fdist, fpsb, sE, (int*)(sE + 8), blockIdx.x, 801, 951, tid);
    return;
  }
  const int blk = blockIdx.x - 8;
  const int b = blk >> 10;
  const int n0 = (blk & 1023) * 4;
  const int rowbase = blk * 64;
  build_e2_tile<RECOMP>(sE, b, n0, rowbase, tid, Q, R, idx, w2, b2, h2, stats);
  const int g = tid & 15;
  const int col0 = (tid >> 4) * 2;
  float a0 = 0.f, a1 = 0.f, a2 = 0.f, a3 = 0.f, b0 = 0.f, b1v = 0.f, b2v = 0.f, b3 = 0.f;
#pragma unroll 4
  for (int c = 0; c < CO; ++c) {
    float e0 = sE[g * 132 + c];
    float e1 = sE[(g + 16) * 132 + c];
    float e2 = sE[(g + 32) * 132 + c];
    float e3 = sE[(g + 48) * 132 + c];
    float2 w = *(const float2*)(wa1 + c * 32 + col0);
    a0 = fmaf(e0, w.x, a0); b0 = fmaf(e0, w.y, b0);
    a1 = fmaf(e1, w.x, a1); b1v = fmaf(e1, w.y, b1v);
    a2 = fmaf(e2, w.x, a2); b2v = fmaf(e2, w.y, b2v);
    a3 = fmaf(e3, w.x, a3); b3 = fmaf(e3, w.y, b3);
  }
  const float2 bb = *(const float2*)(ba1 + col0);
  float s2[2] = {0.f, 0.f}, q2[2] = {0.f, 0.f};
  float va[4] = {a0 + bb.x, a1 + bb.x, a2 + bb.x, a3 + bb.x};
  float vb[4] = {b0 + bb.y, b1v + bb.y, b2v + bb.y, b3 + bb.y};
#pragma unroll
  for (int i = 0; i < 4; ++i) {
    if constexpr (STORET) {
      *(float2*)(t + (size_t)(rowbase + g + 16 * i) * 32 + col0) = make_float2(va[i], vb[i]);
    }
    s2[0] += va[i]; q2[0] = fmaf(va[i], va[i], q2[0]);
    s2[1] += vb[i]; q2[1] = fmaf(vb[i], vb[i], q2[1]);
  }
  __syncthreads();
  float* sS = sE;
  sS[g * 32 + col0] = s2[0];
  sS[g * 32 + col0 + 1] = s2[1];
  sS[512 + g * 32 + col0] = q2[0];
  sS[512 + g * 32 + col0 + 1] = q2[1];
  __syncthreads();
  if (tid < 32) {
    float ss = 0.f, qq = 0.f;
#pragma unroll
    for (int gg = 0; gg < 16; ++gg) {
      ss += sS[gg * 32 + tid];
      qq += sS[512 + gg * 32 + tid];
    }
    parta[blk * 64 + tid] = ss;
    parta[blk * 64 + 32 + tid] = qq;
  }
}

// ------------------------------------------------- K5: softmax + out --------
template <bool RECOMP, bool LOADT>
__global__ __launch_bounds__(256) void k5_out(
    const float* __restrict__ Q, const float* __restrict__ R,
    const int* __restrict__ idx, const float* __restrict__ w2,
    const float* __restrict__ b2, const float* __restrict__ h2,
    const float* __restrict__ t, const float* __restrict__ wa1,
    const float* __restrict__ ba1, const float* __restrict__ wa2,
    const float* __restrict__ ba2, const float* __restrict__ stats,
    float* __restrict__ out, const float* __restrict__ xyz,
    float* __restrict__ fdist, int* __restrict__ fpsb) {
  __shared__ float sE[64 * 132];
  __shared__ float sA[64];
  const int tid = threadIdx.x;
  if (blockIdx.x < 8) {
    fps_chunk(xyz, fdist, fpsb, sE, (int*)(sE + 8), blockIdx.x, 951, 1024, tid);
    return;
  }
  const int blk = blockIdx.x - 8;
  const int b = blk >> 10;
  const int n0 = (blk & 1023) * 4;
  const int rowbase = blk * 64;
  build_e2_tile<RECOMP>(sE, b, n0, rowbase, tid, Q, R, idx, w2, b2, h2, stats);
  const float* sna = stats + 512;
  const float* sha = stats + 544;
  {
    const int r = tid >> 2, q = tid & 3;
    float a2 = 0.f;
    if constexpr (LOADT) {
      const float* tp = t + (size_t)(rowbase + r) * 32 + q * 8;
#pragma unroll
      for (int j = 0; j < 8; j += 4) {
        float4 tv = *(const float4*)(tp + j);
        float4 s4 = *(const float4*)(sna + q * 8 + j);
        float4 h4 = *(const float4*)(sha + q * 8 + j);
        a2 = fmaf(fmaxf(0.f, fmaf(tv.x, s4.x, h4.x)), wa2[q * 8 + j], a2);
        a2 = fmaf(fmaxf(0.f, fmaf(tv.y, s4.y, h4.y)), wa2[q * 8 + j + 1], a2);
        a2 = fmaf(fmaxf(0.f, fmaf(tv.z, s4.z, h4.z)), wa2[q * 8 + j + 2], a2);
        a2 = fmaf(fmaxf(0.f, fmaf(tv.w, s4.w, h4.w)), wa2[q * 8 + j + 3], a2);
      }
    } else {
      float tj[8];
      const float4 bA = *(const float4*)(ba1 + q * 8);
      const float4 bB = *(const float4*)(ba1 + q * 8 + 4);
      tj[0] = bA.x; tj[1] = bA.y; tj[2] = bA.z; tj[3] = bA.w;
      tj[4] = bB.x; tj[5] = bB.y; tj[6] = bB.z; tj[7] = bB.w;
      for (int c = 0; c < CO; ++c) {
        float e = sE[r * 132 + c];
        const float4 wA = *(const float4*)(wa1 + c * 32 + q * 8);
        const float4 wB = *(const float4*)(wa1 + c * 32 + q * 8 + 4);
        tj[0] = fmaf(e, wA.x, tj[0]); tj[1] = fmaf(e, wA.y, tj[1]);
        tj[2] = fmaf(e, wA.z, tj[2]); tj[3] = fmaf(e, wA.w, tj[3]);
        tj[4] = fmaf(e, wB.x, tj[4]); tj[5] = fmaf(e, wB.y, tj[5]);
        tj[6] = fmaf(e, wB.z, tj[6]); tj[7] = fmaf(e, wB.w, tj[7]);
      }
#pragma unroll
      for (int j = 0; j < 8; ++j)
        a2 = fmaf(fmaxf(0.f, fmaf(tj[j], sna[q * 8 + j], sha[q * 8 + j])),
                  wa2[q * 8 + j], a2);
    }
    a2 += __shfl_xor(a2, 1);
    a2 += __shfl_xor(a2, 2);
    a2 += ba2[0];
    float m = a2;
#pragma unroll
    for (int off = 4; off < 64; off <<= 1) m = fmaxf(m, __shfl_xor(m, off));
    float p = expf(a2 - m);
    float s = p;
#pragma unroll
    for (int off = 4; off < 64; off <<= 1) s += __shfl_xor(s, off);
    if (q == 0) sA[r] = p / s;
  }
  __syncthreads();
  const int np2 = tid >> 6;
  const int cg = tid & 63;
  const int c0 = cg * 2;
  float o0 = 0.f, o1 = 0.f;
#pragma unroll
  for (int k = 0; k < 16; ++k) {
    float aw = sA[np2 * 16 + k];
    o0 = fmaf(aw, sE[(np2 * 16 + k) * 132 + c0], o0);
    o1 = fmaf(aw, sE[(np2 * 16 + k) * 132 + c0 + 1], o1);
  }
  float* op = out + (size_t)(b * NN + n0 + np2) * CO + c0;
  *(float2*)op = make_float2(o0, o1);
}

// ------------------------------------------------- K6: gather stats ---------
__global__ __launch_bounds__(256) void k6_gstats(const float* __restrict__ out,
                                                 const int* __restrict__ fps,
                                                 float* __restrict__ partf) {
  __shared__ float red[512];
  const int blk = blockIdx.x;
  const int tid = threadIdx.x;
  const int c = tid & 127;
  const int half = tid >> 7;
  float s = 0.f, q = 0.f;
  for (int i = 0; i < 128; ++i) {
    int row = blk * 256 + half * 128 + i;
    int b = row >> 10, p = row & 1023;
    int fi = fps[b * NP + p];
    float v = out[(size_t)(b * NN + fi) * CO + c];
    s += v;
    q = fmaf(v, v, q);
  }
  red[tid] = s;
  red[256 + tid] = q;
  __syncthreads();
  if (tid < 128) {
    partf[blk * 256 + tid] = red[tid] + red[tid + 128];
    partf[blk * 256 + 128 + tid] = red[256 + tid] + red[256 + tid + 128];
  }
}

// ------------------------------------------------- K7: final outputs --------
__global__ __launch_bounds__(256) void k7_final(const float* __restrict__ xyz,
                                                const float* __restrict__ out,
                                                const int* __restrict__ fps,
                                                const float* __restrict__ stats,
                                                float* __restrict__ dout) {
  const int gid = blockIdx.x * 256 + threadIdx.x;
  const int NX = BB * 3 * NP;  // 24576
  if (gid < NX) {
    int b = gid / 3072;
    int rem = gid - b * 3072;
    int d = rem >> 10, p = rem & 1023;
    int fi = fps[b * NP + p];
    dout[gid] = xyz[(b * 3 + d) * NN + fi];
  } else {
    int h = gid - NX;
    if (h < BB * CO * NP) {
      int b = h >> 17;
      int c = (h >> 10) & 127;
      int p = h & 1023;
      int fi = fps[b * NP + p];
      float v = out[(size_t)(b * NN + fi) * CO + c];
      dout[gid] = fmaf(v, stats[576 + c], stats[704 + c]);
    }
  }
}

// ---------------------------------------------------------------------------
extern "C" void kernel_launch(void* const* d_in, const int* in_sizes, int n_in,
                              void* d_out, int out_size, void* d_ws, size_t ws_size,
                              hipStream_t stream) {
  const float* xyz = (const float*)d_in[0];
  const float* feat = (const float*)d_in[1];
  const float* w1 = (const float*)d_in[2];
  const float* b1 = (const float*)d_in[3];
  const float* g1 = (const float*)d_in[4];
  const float* be1 = (const float*)d_in[5];
  const float* w2 = (const float*)d_in[6];
  const float* b2 = (const float*)d_in[7];
  const float* g2 = (const float*)d_in[8];
  const float* be2 = (const float*)d_in[9];
  const float* wa1 = (const float*)d_in[10];
  const float* ba1 = (const float*)d_in[11];
  const float* ga = (const float*)d_in[12];
  const float* bea = (const float*)d_in[13];
  const float* wa2 = (const float*)d_in[14];
  const float* ba2 = (const float*)d_in[15];
  const float* gf = (const float*)d_in[16];
  const float* bf = (const float*)d_in[17];
  float* outp = (float*)d_out;

  char* ws = (char*)d_ws;
  size_t off = 0;
  auto alloc = [&](size_t bytes) -> void* {
    void* p = ws + off;
    off = (off + bytes + 255) & ~(size_t)255;
    return p;
  };
  unsigned long long* part = (unsigned long long*)alloc((size_t)BB * NN * 128 * 8);  // 33.5 MB
  int* idx = (int*)alloc((size_t)BB * NN * KNb * 4);
  int* fpsb = (int*)alloc((size_t)BB * NP * 4);
  float* fdist = (float*)alloc((size_t)BB * NN * 4);  // FPS state
  float* Q = (float*)alloc((size_t)BB * NN * CO * 4);
  float* R = (float*)alloc((size_t)BB * NN * CO * 4);
  float* ob = (float*)alloc((size_t)BB * NN * CO * 4);
  float* part1 = (float*)alloc((size_t)512 * 256 * 4);
  float* part2 = (float*)alloc((size_t)8192 * 256 * 4);
  float* parta = (float*)alloc((size_t)8192 * 64 * 4);
  float* partf = (float*)alloc((size_t)32 * 256 * 4);
  float* stats = (float*)alloc((size_t)1024 * 4);
  const size_t h2_bytes = (size_t)BB * NN * KNb * CO * 4;  // 268 MB
  const size_t t_bytes = (size_t)BB * NN * KNb * 32 * 4;   // 67 MB
  const bool has_h2 = (off + h2_bytes + 256 <= ws_size);
  float* h2 = has_h2 ? (float*)alloc(h2_bytes) : nullptr;
  const bool has_t = (off + t_bytes + 256 <= ws_size);
  float* tb = has_t ? (float*)alloc(t_bytes) : nullptr;

  const float CNT1 = (float)(BB * NN * KNb);
  front_kernel<<<8 + 1024 + 512, 256, 0, stream>>>(xyz, feat, w1, b1, part, Q, R, fdist, fpsb);
  k2m_kernel<<<8 + 512, 256, 0, stream>>>(xyz, part, Q, R, idx, part1, fdist, fpsb);
  reduce_stats_t<128><<<1, 1024, 0, stream>>>(part1, 512, g1, be1, CNT1, stats, stats + 128);
  if (has_h2)
    k3_mm2<true><<<8 + 8192, 256, 0, stream>>>(Q, R, idx, w2, b2, stats, h2, part2, xyz, fdist, fpsb);
  else
    k3_mm2<false><<<8 + 8192, 256, 0, stream>>>(Q, R, idx, w2, b2, stats, h2, part2, xyz, fdist, fpsb);
  reduce_stats_t<128><<<1, 1024, 0, stream>>>(part2, 8192, g2, be2, CNT1, stats + 256, stats + 384);
  if (has_h2 && has_t)
    k4_attn1<false, true><<<8 + 8192, 256, 0, stream>>>(Q, R, idx, w2, b2, h2, wa1, ba1, stats, tb, parta, xyz, fdist, fpsb);
  else if (has_h2)
    k4_attn1<false, false><<<8 + 8192, 256, 0, stream>>>(Q, R, idx, w2, b2, h2, wa1, ba1, stats, tb, parta, xyz, fdist, fpsb);
  else if (has_t)
    k4_attn1<true, true><<<8 + 8192, 256, 0, stream>>>(Q, R, idx, w2, b2, h2, wa1, ba1, stats, tb, parta, xyz, fdist, fpsb);
  else
    k4_attn1<true, false><<<8 + 8192, 256, 0, stream>>>(Q, R, idx, w2, b2, h2, wa1, ba1, stats, tb, parta, xyz, fdist, fpsb);
  reduce_stats_t<32><<<1, 256, 0, stream>>>(parta, 8192, ga, bea, CNT1, stats + 512, stats + 544);
  if (has_h2 && has_t)
    k5_out<false, true><<<8 + 8192, 256, 0, stream>>>(Q, R, idx, w2, b2, h2, tb, wa1, ba1, wa2, ba2, stats, ob, xyz, fdist, fpsb);
  else if (has_h2)
    k5_out<false, false><<<8 + 8192, 256, 0, stream>>>(Q, R, idx, w2, b2, h2, tb, wa1, ba1, wa2, ba2, stats, ob, xyz, fdist, fpsb);
  else if (has_t)
    k5_out<true, true><<<8 + 8192, 256, 0, stream>>>(Q, R, idx, w2, b2, h2, tb, wa1, ba1, wa2, ba2, stats, ob, xyz, fdist, fpsb);
  else
    k5_out<true, false><<<8 + 8192, 256, 0, stream>>>(Q, R, idx, w2, b2, h2, tb, wa1, ba1, wa2, ba2, stats, ob, xyz, fdist, fpsb);
  k6_gstats<<<32, 256, 0, stream>>>(ob, fpsb, partf);
  reduce_stats_t<128><<<1, 1024, 0, stream>>>(partf, 32, gf, bf, (float)(BB * NP), stats + 576, stats + 704);
  k7_final<<<4192, 256, 0, stream>>>(xyz, ob, fpsb, stats, outp);
}

// Round 5
// 2475.407 us; speedup vs baseline: 1.5182x; 1.0845x over previous
//
#include <hip/hip_runtime.h>
#include <math.h>

// ---------------------------------------------------------------------------
// SetAbstraction (PointNet++-style) for MI355X.
//   front : fps chunk (8) + KNN 2048-cand substream top-16 (256) + k1 Q/R (512)
//   k2m   : fps chunk + 2-way merge -> idx + BN1 partials
//   k3    : fps chunk + e1=relu(bn1(h1)); h2=e1@w2+b2; BN2 partials
//   k4    : fps chunk + e2 tile; t=e2@wa1+ba1; BNa partials
//   k5    : fps chunk + softmax_K; out=sum_k a*e2
//   k6/k7 : gather stats + final outputs
// Two-stage reduce for big partials. FPS serial chain staged across launches.
// ---------------------------------------------------------------------------

#define BB 8
#define NN 4096
#define CIN 64
#define CO 128
#define KNb 16
#define NP 1024

__device__ __forceinline__ float4 bnrelu4(float4 v, float4 s, float4 h) {
  float4 e;
  e.x = fmaxf(0.f, fmaf(v.x, s.x, h.x));
  e.y = fmaxf(0.f, fmaf(v.y, s.y, h.y));
  e.z = fmaxf(0.f, fmaf(v.z, s.z, h.z));
  e.w = fmaxf(0.f, fmaf(v.w, s.w, h.w));
  return e;
}

// ---------------- DPP wave(64) reductions: result broadcast via readlane ----
__device__ __forceinline__ float wave_fmax_bcast(float x) {
#define DPPF(ctrl, rmask)                                                        \
  {                                                                              \
    int t_ = __builtin_amdgcn_update_dpp(0xff800000, __float_as_int(x), ctrl,    \
                                         rmask, 0xf, false);                     \
    x = fmaxf(x, __int_as_float(t_));                                            \
  }
  DPPF(0x111, 0xf) DPPF(0x112, 0xf) DPPF(0x114, 0xf) DPPF(0x118, 0xf)
  DPPF(0x142, 0xa) DPPF(0x143, 0xc)
#undef DPPF
  return __int_as_float(__builtin_amdgcn_readlane(__float_as_int(x), 63));
}
__device__ __forceinline__ unsigned wave_umin_bcast(unsigned x) {
#define DPPU(ctrl, rmask)                                                        \
  {                                                                              \
    unsigned t_ = (unsigned)__builtin_amdgcn_update_dpp(-1, (int)x, ctrl, rmask, \
                                                        0xf, false);             \
    x = (t_ < x) ? t_ : x;                                                       \
  }
  DPPU(0x111, 0xf) DPPU(0x112, 0xf) DPPU(0x114, 0xf) DPPU(0x118, 0xf)
  DPPU(0x142, 0xa) DPPU(0x143, 0xc)
#undef DPPU
  return (unsigned)__builtin_amdgcn_readlane((int)x, 63);
}

// ---------------- FPS chunk: iters [s0,s1), state in fdist / fps[] ----------
__device__ void fps_chunk(const float* __restrict__ xyz, float* __restrict__ fdist,
                          int* __restrict__ fpsb, float* slotF, int* slotP,
                          int b, int s0, int s1, int tid) {
  const float* xb = xyz + b * 3 * NN;
  float px[16], py[16], pz[16], dist[16];
#pragma unroll
  for (int i = 0; i < 16; ++i) {
    int p = i * 256 + tid;
    px[i] = xb[p]; py[i] = xb[NN + p]; pz[i] = xb[2 * NN + p];
  }
  int far;
  if (s0 == 1) {
#pragma unroll
    for (int i = 0; i < 16; ++i) dist[i] = 1e10f;
    far = 0;
    if (tid == 0) fpsb[b * NP] = 0;
  } else {
#pragma unroll
    for (int i = 0; i < 16; ++i) dist[i] = fdist[b * NN + i * 256 + tid];
    far = fpsb[b * NP + s0 - 1];
  }
  for (int s = s0; s < s1; ++s) {
    const float cx = xb[far], cy = xb[NN + far], cz = xb[2 * NN + far];
    float lm = -3.4e38f;
    int lp = 0x7FFFFFFF;
#pragma unroll
    for (int i = 0; i < 16; ++i) {
      float dx = __fsub_rn(px[i], cx);
      float dy = __fsub_rn(py[i], cy);
      float dz = __fsub_rn(pz[i], cz);
      float d = __fadd_rn(__fadd_rn(__fmul_rn(dx, dx), __fmul_rn(dy, dy)),
                          __fmul_rn(dz, dz));
      float nd = fminf(dist[i], d);
      dist[i] = nd;
      bool gt = nd > lm;  // strict >: earliest (lowest) index kept
      lm = gt ? nd : lm;
      lp = gt ? (i * 256 + tid) : lp;
    }
    float wm = wave_fmax_bcast(lm);
    unsigned cand = (lm == wm) ? (unsigned)lp : 0xFFFFFFFFu;
    unsigned wp = wave_umin_bcast(cand);
    const int w = tid >> 6, par = (s & 1) * 4;
    if ((tid & 63) == 0) { slotF[par + w] = wm; slotP[par + w] = (int)wp; }
    __syncthreads();
    float bf = slotF[par]; int bp = slotP[par];
#pragma unroll
    for (int w2 = 1; w2 < 4; ++w2) {
      float f = slotF[par + w2]; int p = slotP[par + w2];
      if (f > bf || (f == bf && p < bp)) { bf = f; bp = p; }
    }
    far = bp;
    if (tid == 0) fpsb[b * NP + s] = far;
  }
#pragma unroll
  for (int i = 0; i < 16; ++i) fdist[b * NN + i * 256 + tid] = dist[i];
}

// ---------------- front: fps(8) + knn partial(256) + k1(512) ----------------
__global__ __launch_bounds__(256) void front_kernel(
    const float* __restrict__ xyz, const float* __restrict__ feat,
    const float* __restrict__ w1, const float* __restrict__ b1,
    unsigned long long* __restrict__ part, float* __restrict__ Q,
    float* __restrict__ R, float* __restrict__ fdist, int* __restrict__ fpsb) {
  __shared__ __align__(16) float smem[8192];  // 32 KB
  const int blk = blockIdx.x;
  const int tid = threadIdx.x;
  if (blk < 8) {
    fps_chunk(xyz, fdist, fpsb, smem, (int*)(smem + 8), blk, 1, 401, tid);
  } else if (blk < 8 + 256) {
    // ---- KNN partial: 256 rows/block, 2048-candidate substream in LDS ----
    const int blkk = blk - 8;
    const int b = blkk >> 5;
    const int rem = blkk & 31;
    const int n0 = (rem >> 1) * 256;  // row tile base
    const int sub = rem & 1;
    const int m0 = sub * 2048;        // candidate range base
    const float* xb = xyz + b * 3 * NN;
    float4* cand = (float4*)smem;     // 2048 float4 = 32 KB
#pragma unroll
    for (int i = 0; i < 8; ++i) {
      int local = i * 256 + tid;
      int m = m0 + local;
      float x = xb[m], y = xb[NN + m], z = xb[2 * NN + m];
      float sq = __fadd_rn(__fadd_rn(__fmul_rn(x, x), __fmul_rn(y, y)),
                           __fmul_rn(z, z));
      cand[local] = make_float4(x, y, z, sq);
    }
    const int n = n0 + tid;
    const float xn = xb[n], yn = xb[NN + n], zn = xb[2 * NN + n];
    const float sqn = __fadd_rn(__fadd_rn(__fmul_rn(xn, xn), __fmul_rn(yn, yn)),
                                __fmul_rn(zn, zn));
    float bd[16];
    int bi[16];
#pragma unroll
    for (int j = 0; j < 16; ++j) { bd[j] = 3.4e38f; bi[j] = 0; }
    __syncthreads();
    for (int mm = 0; mm < 2048; ++mm) {
      float4 pm = cand[mm];
      float dot = fmaf(zn, pm.z, fmaf(yn, pm.y, __fmul_rn(xn, pm.x)));
      float d = __fsub_rn(__fadd_rn(sqn, pm.w), __fmul_rn(2.0f, dot));
      if (d < bd[15]) {  // strict <: equal dist keeps earlier (lower) index
        float cd = d;
        int ci = m0 + mm;
#pragma unroll
        for (int j = 0; j < 16; ++j) {
          bool lt = cd < bd[j];
          float fm = lt ? cd : bd[j];
          cd = lt ? bd[j] : cd;
          bd[j] = fm;
          int im = lt ? ci : bi[j];
          ci = lt ? bi[j] : ci;
          bi[j] = im;
        }
      }
    }
    // pack sortable u64 keys (d asc, idx asc) and store
    unsigned long long* op = part + (size_t)(b * NN + n) * 32 + sub * 16;
#pragma unroll
    for (int j = 0; j < 16; ++j) {
      unsigned ub = __float_as_uint(bd[j]);
      unsigned su = (bd[j] >= 0.f) ? (ub | 0x80000000u) : ~ub;
      op[j] = ((unsigned long long)su << 32) | (unsigned)bi[j];
    }
  } else {
    // ---- k1: Q,R projections ----
    const int blkk = blk - (8 + 256);
    const int b = blkk >> 6;
    const int n0 = (blkk & 63) << 6;
    float* sf = smem;  // [64][65]
#pragma unroll
    for (int i = 0; i < 16; ++i) {
      int lin = i * 256 + tid;
      int c = lin >> 6, nn2 = lin & 63;
      sf[c * 65 + nn2] = feat[(b * CIN + c) * NN + n0 + nn2];
    }
    __syncthreads();
    const int n = tid & 63;
    const int col0 = (tid >> 6) * 32;
    float qa[32], ra[32];
#pragma unroll
    for (int j = 0; j < 32; ++j) { qa[j] = 0.f; ra[j] = 0.f; }
    for (int c = 0; c < CIN; ++c) {
      float f = sf[c * 65 + n];
      const float4* wq = (const float4*)(w1 + c * CO + col0);
      const float4* wr = (const float4*)(w1 + (CIN + c) * CO + col0);
#pragma unroll
      for (int j = 0; j < 8; ++j) {
        float4 a = wq[j];
        float4 bb = wr[j];
        qa[4 * j + 0] = fmaf(f, a.x, qa[4 * j + 0]);
        qa[4 * j + 1] = fmaf(f, a.y, qa[4 * j + 1]);
        qa[4 * j + 2] = fmaf(f, a.z, qa[4 * j + 2]);
        qa[4 * j + 3] = fmaf(f, a.w, qa[4 * j + 3]);
        ra[4 * j + 0] = fmaf(f, bb.x, ra[4 * j + 0]);
        ra[4 * j + 1] = fmaf(f, bb.y, ra[4 * j + 1]);
        ra[4 * j + 2] = fmaf(f, bb.z, ra[4 * j + 2]);
        ra[4 * j + 3] = fmaf(f, bb.w, ra[4 * j + 3]);
      }
    }
    const float* xb = xyz + b * 3 * NN;
    const float xx = xb[n0 + n], yy = xb[NN + n0 + n], zz = xb[2 * NN + n0 + n];
#pragma unroll
    for (int j = 0; j < 32; ++j) {
      int col = col0 + j;
      float xp = fmaf(zz, w1[130 * CO + col],
                      fmaf(yy, w1[129 * CO + col], __fmul_rn(xx, w1[128 * CO + col])));
      qa[j] = qa[j] - xp + b1[col];
      ra[j] = ra[j] + xp;
    }
    float* qp = Q + (size_t)(b * NN + n0 + n) * CO + col0;
    float* rp = R + (size_t)(b * NN + n0 + n) * CO + col0;
#pragma unroll
    for (int j = 0; j < 8; ++j) {
      ((float4*)qp)[j] = make_float4(qa[4 * j], qa[4 * j + 1], qa[4 * j + 2], qa[4 * j + 3]);
      ((float4*)rp)[j] = make_float4(ra[4 * j], ra[4 * j + 1], ra[4 * j + 2], ra[4 * j + 3]);
    }
  }
}

// ---------------- k2m: fps(8) + 2-way merge->idx + BN1 partials -------------
__global__ __launch_bounds__(256) void k2m_kernel(
    const float* __restrict__ xyz, const unsigned long long* __restrict__ part,
    const float* __restrict__ Q, const float* __restrict__ R,
    int* __restrict__ idx, float* __restrict__ part1, float* __restrict__ fdist,
    int* __restrict__ fpsb) {
  __shared__ int smIdx[1024];
  __shared__ float red[512];
  const int blk = blockIdx.x;
  const int tid = threadIdx.x;
  if (blk < 8) {
    fps_chunk(xyz, fdist, fpsb, red, (int*)(red + 8), blk, 401, 501, tid);
    return;
  }
  const int blkk = blk - 8;
  const int b = blkk >> 6;
  const int n0 = (blkk & 63) * 64;
  // phase A: 2-way merge of sorted 16-lists (u64 keys unique; <= picks stream0)
  if (tid < 64) {
    const int row = n0 + tid;
    const unsigned long long* lp = part + (size_t)(b * NN + row) * 32;
    int i = 0, j = 0;
    int* op = idx + (b * NN + row) * KNb;
#pragma unroll
    for (int o = 0; o < 16; ++o) {  // i+j==o<=15 -> both in range
      unsigned long long a = lp[i], c = lp[16 + j];
      int m;
      if (a <= c) { m = (int)(unsigned)(a & 0xFFFFFFFFull); ++i; }
      else { m = (int)(unsigned)(c & 0xFFFFFFFFull); ++j; }
      smIdx[tid * 16 + o] = m;
      op[o] = m;
    }
  }
  __syncthreads();
  // phase B: BN1 stats over h1 = Q[n] + R[m]
  const int c = tid & 127;
  const int sub = tid >> 7;
  float s = 0.f, q = 0.f;
  for (int nn2 = 0; nn2 < 32; ++nn2) {
    int rl = sub * 32 + nn2;
    int n = n0 + rl;
    float qv = Q[(size_t)(b * NN + n) * CO + c];
#pragma unroll
    for (int k = 0; k < KNb; ++k) {
      int m = smIdx[rl * 16 + k];
      float v = qv + R[(size_t)(b * NN + m) * CO + c];
      s += v;
      q = fmaf(v, v, q);
    }
  }
  red[tid] = s;
  __syncthreads();
  float qsave = q;
  if (tid < 128) part1[blkk * 256 + tid] = red[tid] + red[tid + 128];
  __syncthreads();
  red[tid] = qsave;
  __syncthreads();
  if (tid < 128) part1[blkk * 256 + 128 + tid] = red[tid] + red[tid + 128];
}

// ------------------------------------------------- stats reduce -------------
template <int C>
__global__ void reduceA_t(const float* __restrict__ part, float* __restrict__ mid,
                          int nsrc) {
  // grid 64, block 2C; block i double-sums rows [i*chunk, (i+1)*chunk)
  const int i = blockIdx.x;
  const int tid = threadIdx.x;
  const int chunk = nsrc >> 6;
  double s = 0.0;
  const float* p = part + (size_t)i * chunk * 2 * C + tid;
  for (int k = 0; k < chunk; ++k) s += (double)p[(size_t)k * 2 * C];
  mid[i * 2 * C + tid] = (float)s;
}

template <int C>
__global__ void reduce_stats_t(const float* __restrict__ part, int nblk,
                               const float* __restrict__ gamma,
                               const float* __restrict__ beta, float cnt,
                               float* __restrict__ scale, float* __restrict__ shift) {
  __shared__ double redS[8 * C];
  __shared__ double redQ[8 * C];
  const int tid = threadIdx.x;
  const int c = tid % C;
  const int sub = tid / C;
  double s = 0.0, q = 0.0;
  for (int i = sub; i < nblk; i += 8) {
    s += (double)part[i * 2 * C + c];
    q += (double)part[i * 2 * C + C + c];
  }
  redS[sub * C + c] = s;
  redQ[sub * C + c] = q;
  __syncthreads();
  if (tid < C) {
    double ss = 0.0, qq = 0.0;
#pragma unroll
    for (int k = 0; k < 8; ++k) { ss += redS[k * C + tid]; qq += redQ[k * C + tid]; }
    double mean = ss / (double)cnt;
    double var = qq / (double)cnt - mean * mean;
    float inv = 1.0f / sqrtf((float)var + 1e-5f);
    float sc = gamma[tid] * inv;
    scale[tid] = sc;
    shift[tid] = fmaf(-(float)mean, sc, beta[tid]);
  }
}

// ------------------------------------------------- K3: layer2 GEMM ----------
template <bool STOREH2>
__global__ __launch_bounds__(256) void k3_mm2(const float* __restrict__ Q,
                                              const float* __restrict__ R,
                                              const int* __restrict__ idx,
                                              const float* __restrict__ w2,
                                              const float* __restrict__ b2,
                                              const float* __restrict__ stats,
                                              float* __restrict__ h2,
                                              float* __restrict__ part2,
                                              const float* __restrict__ xyz,
                                              float* __restrict__ fdist,
                                              int* __restrict__ fpsb) {
  __shared__ float sE[64 * 132];
  const int tid = threadIdx.x;
  if (blockIdx.x < 8) {
    fps_chunk(xyz, fdist, fpsb, sE, (int*)(sE + 8), blockIdx.x, 501, 801, tid);
    return;
  }
  const int blk = blockIdx.x - 8;
  const int b = blk >> 10;
  const int n0 = (blk & 1023) * 4;
  const int rowbase = blk * 64;
  const float* scale1 = stats;
  const float* shift1 = stats + 128;
  {
    const int r = tid >> 2, c0 = (tid & 3) * 32;
    const int np2 = r >> 4, k = r & 15;
    const int n = n0 + np2;
    const int m = idx[(b * NN + n) * KNb + k];
    const float4* qp = (const float4*)(Q + (size_t)(b * NN + n) * CO + c0);
    const float4* rp = (const float4*)(R + (size_t)(b * NN + m) * CO + c0);
    const float4* s4p = (const float4*)(scale1 + c0);
    const float4* h4p = (const float4*)(shift1 + c0);
    float* se = sE + r * 132 + c0;
#pragma unroll
    for (int j = 0; j < 8; ++j) {
      float4 a = qp[j];
      float4 bb = rp[j];
      float4 v = make_float4(a.x + bb.x, a.y + bb.y, a.z + bb.z, a.w + bb.w);
      ((float4*)se)[j] = bnrelu4(v, s4p[j], h4p[j]);
    }
  }
  __syncthreads();
  const int g = tid & 15;
  const int col0 = (tid >> 4) * 8;
  float acc[4][8];
#pragma unroll
  for (int i = 0; i < 4; ++i)
#pragma unroll
    for (int j = 0; j < 8; ++j) acc[i][j] = 0.f;
#pragma unroll 2
  for (int c = 0; c < CO; ++c) {
    float ev[4];
    ev[0] = sE[g * 132 + c];
    ev[1] = sE[(g + 16) * 132 + c];
    ev[2] = sE[(g + 32) * 132 + c];
    ev[3] = sE[(g + 48) * 132 + c];
    const float4 wa = *(const float4*)(w2 + c * CO + col0);
    const float4 wb = *(const float4*)(w2 + c * CO + col0 + 4);
    const float wv[8] = {wa.x, wa.y, wa.z, wa.w, wb.x, wb.y, wb.z, wb.w};
#pragma unroll
    for (int i = 0; i < 4; ++i)
#pragma unroll
      for (int j = 0; j < 8; ++j) acc[i][j] = fmaf(ev[i], wv[j], acc[i][j]);
  }
  const float4 bA = *(const float4*)(b2 + col0);
  const float4 bB = *(const float4*)(b2 + col0 + 4);
  const float bv[8] = {bA.x, bA.y, bA.z, bA.w, bB.x, bB.y, bB.z, bB.w};
  float bsum[8], bsq[8];
#pragma unroll
  for (int j = 0; j < 8; ++j) { bsum[j] = 0.f; bsq[j] = 0.f; }
#pragma unroll
  for (int i = 0; i < 4; ++i) {
    float v[8];
#pragma unroll
    for (int j = 0; j < 8; ++j) {
      v[j] = acc[i][j] + bv[j];
      bsum[j] += v[j];
      bsq[j] = fmaf(v[j], v[j], bsq[j]);
    }
    if constexpr (STOREH2) {
      float* hp = h2 + (size_t)(rowbase + g + 16 * i) * CO + col0;
      *(float4*)(hp) = make_float4(v[0], v[1], v[2], v[3]);
      *(float4*)(hp + 4) = make_float4(v[4], v[5], v[6], v[7]);
    }
  }
  __syncthreads();
  float* sS = sE;
  float* sQ2 = sE + 2048;
#pragma unroll
  for (int j = 0; j < 8; ++j) {
    sS[g * 128 + col0 + j] = bsum[j];
    sQ2[g * 128 + col0 + j] = bsq[j];
  }
  __syncthreads();
  if (tid < 128) {
    float ss = 0.f, qq = 0.f;
#pragma unroll
    for (int gg = 0; gg < 16; ++gg) {
      ss += sS[gg * 128 + tid];
      qq += sQ2[gg * 128 + tid];
    }
    part2[blk * 256 + tid] = ss;
    part2[blk * 256 + 128 + tid] = qq;
  }
}

// ------------------------------------------------- e2 tile builder ----------
template <bool RECOMP>
__device__ __forceinline__ void build_e2_tile(
    float* sE, const int b, const int n0, const int rowbase, const int tid,
    const float* __restrict__ Q, const float* __restrict__ R,
    const int* __restrict__ idx, const float* __restrict__ w2,
    const float* __restrict__ b2, const float* __restrict__ h2,
    const float* __restrict__ stats) {
  const float* sc2 = stats + 256;
  const float* sh2 = stats + 384;
  const int r = tid >> 2, c0 = (tid & 3) * 32;
  if constexpr (!RECOMP) {
    const float4* hp = (const float4*)(h2 + (size_t)(rowbase + r) * CO + c0);
    const float4* s4p = (const float4*)(sc2 + c0);
    const float4* h4p = (const float4*)(sh2 + c0);
    float* se = sE + r * 132 + c0;
#pragma unroll
    for (int j = 0; j < 8; ++j) ((float4*)se)[j] = bnrelu4(hp[j], s4p[j], h4p[j]);
    __syncthreads();
  } else {
    const float* sc1 = stats;
    const float* sh1 = stats + 128;
    {
      const int np2 = r >> 4, k = r & 15;
      const int n = n0 + np2;
      const int m = idx[(b * NN + n) * KNb + k];
      const float4* qp = (const float4*)(Q + (size_t)(b * NN + n) * CO + c0);
      const float4* rp = (const float4*)(R + (size_t)(b * NN + m) * CO + c0);
      const float4* s4p = (const float4*)(sc1 + c0);
      const float4* h4p = (const float4*)(sh1 + c0);
      float* se = sE + r * 132 + c0;
#pragma unroll
      for (int j = 0; j < 8; ++j) {
        float4 a = qp[j];
        float4 bb = rp[j];
        float4 v = make_float4(a.x + bb.x, a.y + bb.y, a.z + bb.z, a.w + bb.w);
        ((float4*)se)[j] = bnrelu4(v, s4p[j], h4p[j]);
      }
    }
    __syncthreads();
    const int g = tid & 15, col0 = (tid >> 4) * 8;
    float acc[4][8];
#pragma unroll
    for (int i = 0; i < 4; ++i)
#pragma unroll
      for (int j = 0; j < 8; ++j) acc[i][j] = 0.f;
#pragma unroll 2
    for (int c = 0; c < CO; ++c) {
      float ev[4];
      ev[0] = sE[g * 132 + c];
      ev[1] = sE[(g + 16) * 132 + c];
      ev[2] = sE[(g + 32) * 132 + c];
      ev[3] = sE[(g + 48) * 132 + c];
      const float4 wa = *(const float4*)(w2 + c * CO + col0);
      const float4 wb = *(const float4*)(w2 + c * CO + col0 + 4);
      const float wv[8] = {wa.x, wa.y, wa.z, wa.w, wb.x, wb.y, wb.z, wb.w};
#pragma unroll
      for (int i = 0; i < 4; ++i)
#pragma unroll
        for (int j = 0; j < 8; ++j) acc[i][j] = fmaf(ev[i], wv[j], acc[i][j]);
    }
    __syncthreads();  // all reads of e1 done before overwrite
    const float4 bA = *(const float4*)(b2 + col0);
    const float4 bB = *(const float4*)(b2 + col0 + 4);
    const float4 sA4 = *(const float4*)(sc2 + col0);
    const float4 sB4 = *(const float4*)(sc2 + col0 + 4);
    const float4 hA4 = *(const float4*)(sh2 + col0);
    const float4 hB4 = *(const float4*)(sh2 + col0 + 4);
#pragma unroll
    for (int i = 0; i < 4; ++i) {
      float4 v0 = make_float4(acc[i][0] + bA.x, acc[i][1] + bA.y,
                              acc[i][2] + bA.z, acc[i][3] + bA.w);
      float4 v1 = make_float4(acc[i][4] + bB.x, acc[i][5] + bB.y,
                              acc[i][6] + bB.z, acc[i][7] + bB.w);
      float* se = sE + (g + 16 * i) * 132 + col0;
      *(float4*)se = bnrelu4(v0, sA4, hA4);
      *(float4*)(se + 4) = bnrelu4(v1, sB4, hB4);
    }
    __syncthreads();
  }
}

// ------------------------------------------------- K4: attention MLP1 -------
template <bool RECOMP, bool STORET>
__global__ __launch_bounds__(256) void k4_attn1(
    const float* __restrict__ Q, const float* __restrict__ R,
    const int* __restrict__ idx, const float* __restrict__ w2,
    const float* __restrict__ b2, const float* __restrict__ h2,
    const float* __restrict__ wa1, const float* __restrict__ ba1,
    const float* __restrict__ stats, float* __restrict__ t,
    float* __restrict__ parta, const float* __restrict__ xyz,
    float* __restrict__ fdist, int* __restrict__ fpsb) {
  __shared__ float sE[64 * 132];
  const int tid = threadIdx.x;
  if (blockIdx.x < 8) {
    fps_chunk(xyz, fdist, fpsb, sE, (int*)(sE + 8), blockIdx.x, 801, 951, tid);
    return;
  }
  const int blk = blockIdx.x - 8;
  const int b = blk >> 10;
  const int n0 = (blk & 1023) * 4;
  const int rowbase = blk * 64;
  build_e2_tile<RECOMP>(sE, b, n0, rowbase, tid, Q, R, idx, w2, b2, h2, stats);
  const int g = tid & 15;
  const int col0 = (tid >> 4) * 2;
  float a0 = 0.f, a1 = 0.f, a2 = 0.f, a3 = 0.f, b0 = 0.f, b1v = 0.f, b2v = 0.f, b3 = 0.f;
#pragma unroll 4
  for (int c = 0; c < CO; ++c) {
    float e0 = sE[g * 132 + c];
    float e1 = sE[(g + 16) * 132 + c];
    float e2 = sE[(g + 32) * 132 + c];
    float e3 = sE[(g + 48) * 132 + c];
    float2 w = *(const float2*)(wa1 + c * 32 + col0);
    a0 = fmaf(e0, w.x, a0); b0 = fmaf(e0, w.y, b0);
    a1 = fmaf(e1, w.x, a1); b1v = fmaf(e1, w.y, b1v);
    a2 = fmaf(e2, w.x, a2); b2v = fmaf(e2, w.y, b2v);
    a3 = fmaf(e3, w.x, a3); b3 = fmaf(e3, w.y, b3);
  }
  const float2 bb = *(const float2*)(ba1 + col0);
  float s2[2] = {0.f, 0.f}, q2[2] = {0.f, 0.f};
  float va[4] = {a0 + bb.x, a1 + bb.x, a2 + bb.x, a3 + bb.x};
  float vb[4] = {b0 + bb.y, b1v + bb.y, b2v + bb.y, b3 + bb.y};
#pragma unroll
  for (int i = 0; i < 4; ++i) {
    if constexpr (STORET) {
      *(float2*)(t + (size_t)(rowbase + g + 16 * i) * 32 + col0) = make_float2(va[i], vb[i]);
    }
    s2[0] += va[i]; q2[0] = fmaf(va[i], va[i], q2[0]);
    s2[1] += vb[i]; q2[1] = fmaf(vb[i], vb[i], q2[1]);
  }
  __syncthreads();
  float* sS = sE;
  sS[g * 32 + col0] = s2[0];
  sS[g * 32 + col0 + 1] = s2[1];
  sS[512 + g * 32 + col0] = q2[0];
  sS[512 + g * 32 + col0 + 1] = q2[1];
  __syncthreads();
  if (tid < 32) {
    float ss = 0.f, qq = 0.f;
#pragma unroll
    for (int gg = 0; gg < 16; ++gg) {
      ss += sS[gg * 32 + tid];
      qq += sS[512 + gg * 32 + tid];
    }
    parta[blk * 64 + tid] = ss;
    parta[blk * 64 + 32 + tid] = qq;
  }
}

// ------------------------------------------------- K5: softmax + out --------
template <bool RECOMP, bool LOADT>
__global__ __launch_bounds__(256) void k5_out(
    const float* __restrict__ Q, const float* __restrict__ R,
    const int* __restrict__ idx, const float* __restrict__ w2,
    const float* __restrict__ b2, const float* __restrict__ h2,
    const float* __restrict__ t, const float* __restrict__ wa1,
    const float* __restrict__ ba1, const float* __restrict__ wa2,
    const float* __restrict__ ba2, const float* __restrict__ stats,
    float* __restrict__ out, const float* __restrict__ xyz,
    float* __restrict__ fdist, int* __restrict__ fpsb) {
  __shared__ float sE[64 * 132];
  __shared__ float sA[64];
  const int tid = threadIdx.x;
  if (blockIdx.x < 8) {
    fps_chunk(xyz, fdist, fpsb, sE, (int*)(sE + 8), blockIdx.x, 951, 1024, tid);
    return;
  }
  const int blk = blockIdx.x - 8;
  const int b = blk >> 10;
  const int n0 = (blk & 1023) * 4;
  const int rowbase = blk * 64;
  build_e2_tile<RECOMP>(sE, b, n0, rowbase, tid, Q, R, idx, w2, b2, h2, stats);
  const float* sna = stats + 512;
  const float* sha = stats + 544;
  {
    const int r = tid >> 2, q = tid & 3;
    float a2 = 0.f;
    if constexpr (LOADT) {
      const float* tp = t + (size_t)(rowbase + r) * 32 + q * 8;
#pragma unroll
      for (int j = 0; j < 8; j += 4) {
        float4 tv = *(const float4*)(tp + j);
        float4 s4 = *(const float4*)(sna + q * 8 + j);
        float4 h4 = *(const float4*)(sha + q * 8 + j);
        a2 = fmaf(fmaxf(0.f, fmaf(tv.x, s4.x, h4.x)), wa2[q * 8 + j], a2);
        a2 = fmaf(fmaxf(0.f, fmaf(tv.y, s4.y, h4.y)), wa2[q * 8 + j + 1], a2);
        a2 = fmaf(fmaxf(0.f, fmaf(tv.z, s4.z, h4.z)), wa2[q * 8 + j + 2], a2);
        a2 = fmaf(fmaxf(0.f, fmaf(tv.w, s4.w, h4.w)), wa2[q * 8 + j + 3], a2);
      }
    } else {
      float tj[8];
      const float4 bA = *(const float4*)(ba1 + q * 8);
      const float4 bB = *(const float4*)(ba1 + q * 8 + 4);
      tj[0] = bA.x; tj[1] = bA.y; tj[2] = bA.z; tj[3] = bA.w;
      tj[4] = bB.x; tj[5] = bB.y; tj[6] = bB.z; tj[7] = bB.w;
      for (int c = 0; c < CO; ++c) {
        float e = sE[r * 132 + c];
        const float4 wA = *(const float4*)(wa1 + c * 32 + q * 8);
        const float4 wB = *(const float4*)(wa1 + c * 32 + q * 8 + 4);
        tj[0] = fmaf(e, wA.x, tj[0]); tj[1] = fmaf(e, wA.y, tj[1]);
        tj[2] = fmaf(e, wA.z, tj[2]); tj[3] = fmaf(e, wA.w, tj[3]);
        tj[4] = fmaf(e, wB.x, tj[4]); tj[5] = fmaf(e, wB.y, tj[5]);
        tj[6] = fmaf(e, wB.z, tj[6]); tj[7] = fmaf(e, wB.w, tj[7]);
      }
#pragma unroll
      for (int j = 0; j < 8; ++j)
        a2 = fmaf(fmaxf(0.f, fmaf(tj[j], sna[q * 8 + j], sha[q * 8 + j])),
                  wa2[q * 8 + j], a2);
    }
    a2 += __shfl_xor(a2, 1);
    a2 += __shfl_xor(a2, 2);
    a2 += ba2[0];
    float m = a2;
#pragma unroll
    for (int off = 4; off < 64; off <<= 1) m = fmaxf(m, __shfl_xor(m, off));
    float p = expf(a2 - m);
    float s = p;
#pragma unroll
    for (int off = 4; off < 64; off <<= 1) s += __shfl_xor(s, off);
    if (q == 0) sA[r] = p / s;
  }
  __syncthreads();
  const int np2 = tid >> 6;
  const int cg = tid & 63;
  const int c0 = cg * 2;
  float o0 = 0.f, o1 = 0.f;
#pragma unroll
  for (int k = 0; k < 16; ++k) {
    float aw = sA[np2 * 16 + k];
    o0 = fmaf(aw, sE[(np2 * 16 + k) * 132 + c0], o0);
    o1 = fmaf(aw, sE[(np2 * 16 + k) * 132 + c0 + 1], o1);
  }
  float* op = out + (size_t)(b * NN + n0 + np2) * CO + c0;
  *(float2*)op = make_float2(o0, o1);
}

// ------------------------------------------------- K6: gather stats ---------
__global__ __launch_bounds__(256) void k6_gstats(const float* __restrict__ out,
                                                 const int* __restrict__ fps,
                                                 float* __restrict__ partf) {
  __shared__ float red[512];
  const int blk = blockIdx.x;
  const int tid = threadIdx.x;
  const int c = tid & 127;
  const int half = tid >> 7;
  float s = 0.f, q = 0.f;
  for (int i = 0; i < 128; ++i) {
    int row = blk * 256 + half * 128 + i;
    int b = row >> 10, p = row & 1023;
    int fi = fps[b * NP + p];
    float v = out[(size_t)(b * NN + fi) * CO + c];
    s += v;
    q = fmaf(v, v, q);
  }
  red[tid] = s;
  red[256 + tid] = q;
  __syncthreads();
  if (tid < 128) {
    partf[blk * 256 + tid] = red[tid] + red[tid + 128];
    partf[blk * 256 + 128 + tid] = red[256 + tid] + red[256 + tid + 128];
  }
}

// ------------------------------------------------- K7: final outputs --------
__global__ __launch_bounds__(256) void k7_final(const float* __restrict__ xyz,
                                                const float* __restrict__ out,
                                                const int* __restrict__ fps,
                                                const float* __restrict__ stats,
                                                float* __restrict__ dout) {
  const int gid = blockIdx.x * 256 + threadIdx.x;
  const int NX = BB * 3 * NP;  // 24576
  if (gid < NX) {
    int b = gid / 3072;
    int rem = gid - b * 3072;
    int d = rem >> 10, p = rem & 1023;
    int fi = fps[b * NP + p];
    dout[gid] = xyz[(b * 3 + d) * NN + fi];
  } else {
    int h = gid - NX;
    if (h < BB * CO * NP) {
      int b = h >> 17;
      int c = (h >> 10) & 127;
      int p = h & 1023;
      int fi = fps[b * NP + p];
      float v = out[(size_t)(b * NN + fi) * CO + c];
      dout[gid] = fmaf(v, stats[576 + c], stats[704 + c]);
    }
  }
}

// ---------------------------------------------------------------------------
extern "C" void kernel_launch(void* const* d_in, const int* in_sizes, int n_in,
                              void* d_out, int out_size, void* d_ws, size_t ws_size,
                              hipStream_t stream) {
  const float* xyz = (const float*)d_in[0];
  const float* feat = (const float*)d_in[1];
  const float* w1 = (const float*)d_in[2];
  const float* b1 = (const float*)d_in[3];
  const float* g1 = (const float*)d_in[4];
  const float* be1 = (const float*)d_in[5];
  const float* w2 = (const float*)d_in[6];
  const float* b2 = (const float*)d_in[7];
  const float* g2 = (const float*)d_in[8];
  const float* be2 = (const float*)d_in[9];
  const float* wa1 = (const float*)d_in[10];
  const float* ba1 = (const float*)d_in[11];
  const float* ga = (const float*)d_in[12];
  const float* bea = (const float*)d_in[13];
  const float* wa2 = (const float*)d_in[14];
  const float* ba2 = (const float*)d_in[15];
  const float* gf = (const float*)d_in[16];
  const float* bf = (const float*)d_in[17];
  float* outp = (float*)d_out;

  char* ws = (char*)d_ws;
  size_t off = 0;
  auto alloc = [&](size_t bytes) -> void* {
    void* p = ws + off;
    off = (off + bytes + 255) & ~(size_t)255;
    return p;
  };
  unsigned long long* part = (unsigned long long*)alloc((size_t)BB * NN * 32 * 8);  // 8.4 MB
  int* idx = (int*)alloc((size_t)BB * NN * KNb * 4);
  int* fpsb = (int*)alloc((size_t)BB * NP * 4);
  float* fdist = (float*)alloc((size_t)BB * NN * 4);  // FPS state
  float* Q = (float*)alloc((size_t)BB * NN * CO * 4);
  float* R = (float*)alloc((size_t)BB * NN * CO * 4);
  float* ob = (float*)alloc((size_t)BB * NN * CO * 4);
  float* part1 = (float*)alloc((size_t)512 * 256 * 4);
  float* part2 = (float*)alloc((size_t)8192 * 256 * 4);
  float* parta = (float*)alloc((size_t)8192 * 64 * 4);
  float* partf = (float*)alloc((size_t)32 * 256 * 4);
  float* mid2 = (float*)alloc((size_t)64 * 256 * 4);
  float* mida = (float*)alloc((size_t)64 * 64 * 4);
  float* stats = (float*)alloc((size_t)1024 * 4);
  const size_t h2_bytes = (size_t)BB * NN * KNb * CO * 4;  // 268 MB
  const size_t t_bytes = (size_t)BB * NN * KNb * 32 * 4;   // 67 MB
  const bool has_h2 = (off + h2_bytes + 256 <= ws_size);
  float* h2 = has_h2 ? (float*)alloc(h2_bytes) : nullptr;
  const bool has_t = (off + t_bytes + 256 <= ws_size);
  float* tb = has_t ? (float*)alloc(t_bytes) : nullptr;

  const float CNT1 = (float)(BB * NN * KNb);
  front_kernel<<<8 + 256 + 512, 256, 0, stream>>>(xyz, feat, w1, b1, part, Q, R, fdist, fpsb);
  k2m_kernel<<<8 + 512, 256, 0, stream>>>(xyz, part, Q, R, idx, part1, fdist, fpsb);
  reduce_stats_t<128><<<1, 1024, 0, stream>>>(part1, 512, g1, be1, CNT1, stats, stats + 128);
  if (has_h2)
    k3_mm2<true><<<8 + 8192, 256, 0, stream>>>(Q, R, idx, w2, b2, stats, h2, part2, xyz, fdist, fpsb);
  else
    k3_mm2<false><<<8 + 8192, 256, 0, stream>>>(Q, R, idx, w2, b2, stats, h2, part2, xyz, fdist, fpsb);
  reduceA_t<128><<<64, 256, 0, stream>>>(part2, mid2, 8192);
  reduce_stats_t<128><<<1, 1024, 0, stream>>>(mid2, 64, g2, be2, CNT1, stats + 256, stats + 384);
  if (has_h2 && has_t)
    k4_attn1<false, true><<<8 + 8192, 256, 0, stream>>>(Q, R, idx, w2, b2, h2, wa1, ba1, stats, tb, parta, xyz, fdist, fpsb);
  else if (has_h2)
    k4_attn1<false, false><<<8 + 8192, 256, 0, stream>>>(Q, R, idx, w2, b2, h2, wa1, ba1, stats, tb, parta, xyz, fdist, fpsb);
  else if (has_t)
    k4_attn1<true, true><<<8 + 8192, 256, 0, stream>>>(Q, R, idx, w2, b2, h2, wa1, ba1, stats, tb, parta, xyz, fdist, fpsb);
  else
    k4_attn1<true, false><<<8 + 8192, 256, 0, stream>>>(Q, R, idx, w2, b2, h2, wa1, ba1, stats, tb, parta, xyz, fdist, fpsb);
  reduceA_t<32><<<64, 64, 0, stream>>>(parta, mida, 8192);
  reduce_stats_t<32><<<1, 256, 0, stream>>>(mida, 64, ga, bea, CNT1, stats + 512, stats + 544);
  if (has_h2 && has_t)
    k5_out<false, true><<<8 + 8192, 256, 0, stream>>>(Q, R, idx, w2, b2, h2, tb, wa1, ba1, wa2, ba2, stats, ob, xyz, fdist, fpsb);
  else if (has_h2)
    k5_out<false, false><<<8 + 8192, 256, 0, stream>>>(Q, R, idx, w2, b2, h2, tb, wa1, ba1, wa2, ba2, stats, ob, xyz, fdist, fpsb);
  else if (has_t)
    k5_out<true, true><<<8 + 8192, 256, 0, stream>>>(Q, R, idx, w2, b2, h2, tb, wa1, ba1, wa2, ba2, stats, ob, xyz, fdist, fpsb);
  else
    k5_out<true, false><<<8 + 8192, 256, 0, stream>>>(Q, R, idx, w2, b2, h2, tb, wa1, ba1, wa2, ba2, stats, ob, xyz, fdist, fpsb);
  k6_gstats<<<32, 256, 0, stream>>>(ob, fpsb, partf);
  reduce_stats_t<128><<<1, 1024, 0, stream>>>(partf, 32, gf, bf, (float)(BB * NP), stats + 576, stats + 704);
  k7_final<<<4192, 256, 0, stream>>>(xyz, ob, fpsb, stats, outp);
}

// Round 7
// 1903.546 us; speedup vs baseline: 1.9743x; 1.3004x over previous
//
#include <hip/hip_runtime.h>
#include <math.h>

// ---------------------------------------------------------------------------
// SetAbstraction (PointNet++-style) for MI355X.
//   front : fps chunk (8) + KNN 1024-cand substream top-16 (512, branchless
//           parallel-rank insert, 2 waves/SIMD) + k1 Q/R (512)
//   k2m   : fps chunk + 4-way merge -> idx + BN1 partials
//   k3    : fps chunk + e1=relu(bn1(h1)); h2=e1@w2+b2; BN2 partials
//   k4    : fps chunk + e2 tile; t=e2@wa1+ba1; BNa partials
//   k5    : fps chunk + softmax_K; out=sum_k a*e2
//   k6/k7 : gather stats + final outputs
// Two-stage reduce for big partials. FPS serial chain staged across launches.
// ---------------------------------------------------------------------------

#define BB 8
#define NN 4096
#define CIN 64
#define CO 128
#define KNb 16
#define NP 1024

__device__ __forceinline__ float4 bnrelu4(float4 v, float4 s, float4 h) {
  float4 e;
  e.x = fmaxf(0.f, fmaf(v.x, s.x, h.x));
  e.y = fmaxf(0.f, fmaf(v.y, s.y, h.y));
  e.z = fmaxf(0.f, fmaf(v.z, s.z, h.z));
  e.w = fmaxf(0.f, fmaf(v.w, s.w, h.w));
  return e;
}

// ---------------- DPP wave(64) reductions: result broadcast via readlane ----
__device__ __forceinline__ float wave_fmax_bcast(float x) {
#define DPPF(ctrl, rmask)                                                        \
  {                                                                              \
    int t_ = __builtin_amdgcn_update_dpp(0xff800000, __float_as_int(x), ctrl,    \
                                         rmask, 0xf, false);                     \
    x = fmaxf(x, __int_as_float(t_));                                            \
  }
  DPPF(0x111, 0xf) DPPF(0x112, 0xf) DPPF(0x114, 0xf) DPPF(0x118, 0xf)
  DPPF(0x142, 0xa) DPPF(0x143, 0xc)
#undef DPPF
  return __int_as_float(__builtin_amdgcn_readlane(__float_as_int(x), 63));
}
__device__ __forceinline__ unsigned wave_umin_bcast(unsigned x) {
#define DPPU(ctrl, rmask)                                                        \
  {                                                                              \
    unsigned t_ = (unsigned)__builtin_amdgcn_update_dpp(-1, (int)x, ctrl, rmask, \
                                                        0xf, false);             \
    x = (t_ < x) ? t_ : x;                                                       \
  }
  DPPU(0x111, 0xf) DPPU(0x112, 0xf) DPPU(0x114, 0xf) DPPU(0x118, 0xf)
  DPPU(0x142, 0xa) DPPU(0x143, 0xc)
#undef DPPU
  return (unsigned)__builtin_amdgcn_readlane((int)x, 63);
}

// ---------------- FPS chunk: iters [s0,s1), state in fdist / fps[] ----------
__device__ void fps_chunk(const float* __restrict__ xyz, float* __restrict__ fdist,
                          int* __restrict__ fpsb, float* slotF, int* slotP,
                          int b, int s0, int s1, int tid) {
  const float* xb = xyz + b * 3 * NN;
  float px[16], py[16], pz[16], dist[16];
#pragma unroll
  for (int i = 0; i < 16; ++i) {
    int p = i * 256 + tid;
    px[i] = xb[p]; py[i] = xb[NN + p]; pz[i] = xb[2 * NN + p];
  }
  int far;
  if (s0 == 1) {
#pragma unroll
    for (int i = 0; i < 16; ++i) dist[i] = 1e10f;
    far = 0;
    if (tid == 0) fpsb[b * NP] = 0;
  } else {
#pragma unroll
    for (int i = 0; i < 16; ++i) dist[i] = fdist[b * NN + i * 256 + tid];
    far = fpsb[b * NP + s0 - 1];
  }
  for (int s = s0; s < s1; ++s) {
    const float cx = xb[far], cy = xb[NN + far], cz = xb[2 * NN + far];
    float lm = -3.4e38f;
    int lp = 0x7FFFFFFF;
#pragma unroll
    for (int i = 0; i < 16; ++i) {
      float dx = __fsub_rn(px[i], cx);
      float dy = __fsub_rn(py[i], cy);
      float dz = __fsub_rn(pz[i], cz);
      float d = __fadd_rn(__fadd_rn(__fmul_rn(dx, dx), __fmul_rn(dy, dy)),
                          __fmul_rn(dz, dz));
      float nd = fminf(dist[i], d);
      dist[i] = nd;
      bool gt = nd > lm;  // strict >: earliest (lowest) index kept
      lm = gt ? nd : lm;
      lp = gt ? (i * 256 + tid) : lp;
    }
    float wm = wave_fmax_bcast(lm);
    unsigned cand = (lm == wm) ? (unsigned)lp : 0xFFFFFFFFu;
    unsigned wp = wave_umin_bcast(cand);
    const int w = tid >> 6, par = (s & 1) * 4;
    if ((tid & 63) == 0) { slotF[par + w] = wm; slotP[par + w] = (int)wp; }
    __syncthreads();
    float bf = slotF[par]; int bp = slotP[par];
#pragma unroll
    for (int w2 = 1; w2 < 4; ++w2) {
      float f = slotF[par + w2]; int p = slotP[par + w2];
      if (f > bf || (f == bf && p < bp)) { bf = f; bp = p; }
    }
    far = bp;
    if (tid == 0) fpsb[b * NP + s] = far;
  }
#pragma unroll
  for (int i = 0; i < 16; ++i) fdist[b * NN + i * 256 + tid] = dist[i];
}

// ---------------- front: fps(8) + knn partial(512) + k1(512) ----------------
__global__ __launch_bounds__(256) void front_kernel(
    const float* __restrict__ xyz, const float* __restrict__ feat,
    const float* __restrict__ w1, const float* __restrict__ b1,
    unsigned long long* __restrict__ part, float* __restrict__ Q,
    float* __restrict__ R, float* __restrict__ fdist, int* __restrict__ fpsb) {
  __shared__ __align__(16) float smem[4224];  // 16.9 KB
  const int blk = blockIdx.x;
  const int tid = threadIdx.x;
  if (blk < 8) {
    fps_chunk(xyz, fdist, fpsb, smem, (int*)(smem + 8), blk, 1, 401, tid);
  } else if (blk < 8 + 512) {
    // ---- KNN partial: 256 rows/block, 1024-cand substream, branchless ----
    const int blkk = blk - 8;
    const int b = blkk >> 6;
    const int rem = blkk & 63;
    const int n0 = (rem >> 2) << 8;  // row tile base (16 tiles of 256)
    const int m0 = (rem & 3) << 10;  // candidate range base (4 subs of 1024)
    const float* xb = xyz + b * 3 * NN;
    float4* cand = (float4*)smem;    // 1024 float4 = 16 KB
#pragma unroll
    for (int i = 0; i < 4; ++i) {
      int local = i * 256 + tid;
      int m = m0 + local;
      float x = xb[m], y = xb[NN + m], z = xb[2 * NN + m];
      float sq = __fadd_rn(__fadd_rn(__fmul_rn(x, x), __fmul_rn(y, y)),
                           __fmul_rn(z, z));
      cand[local] = make_float4(x, y, z, sq);
    }
    const int n = n0 + tid;
    const float xn = xb[n], yn = xb[NN + n], zn = xb[2 * NN + n];
    const float sqn = __fadd_rn(__fadd_rn(__fmul_rn(xn, xn), __fmul_rn(yn, yn)),
                                __fmul_rn(zn, zn));
    float bd[16];
    int bi[16];
#pragma unroll
    for (int j = 0; j < 16; ++j) { bd[j] = 3.4e38f; bi[j] = 0; }
    __syncthreads();
    for (int mm = 0; mm < 1024; ++mm) {
      float4 pm = cand[mm];
      float dot = fmaf(zn, pm.z, fmaf(yn, pm.y, __fmul_rn(xn, pm.x)));
      float d = __fsub_rn(__fadd_rn(sqn, pm.w), __fmul_rn(2.0f, dot));
      const int ci = m0 + mm;
      // branchless parallel-rank insertion (strict <: ties keep lower index)
      bool c[16];
#pragma unroll
      for (int j = 0; j < 16; ++j) c[j] = d < bd[j];
#pragma unroll
      for (int j = 15; j >= 1; --j) {
        float td = c[j - 1] ? bd[j - 1] : d;
        int ti = c[j - 1] ? bi[j - 1] : ci;
        bd[j] = c[j] ? td : bd[j];
        bi[j] = c[j] ? ti : bi[j];
      }
      bd[0] = c[0] ? d : bd[0];
      bi[0] = c[0] ? ci : bi[0];
    }
    // pack sortable u64 keys (d asc, idx asc) and store
    unsigned long long* op = part + (size_t)(b * NN + n) * 64 + (rem & 3) * 16;
#pragma unroll
    for (int j = 0; j < 16; ++j) {
      unsigned ub = __float_as_uint(bd[j]);
      unsigned su = (bd[j] >= 0.f) ? (ub | 0x80000000u) : ~ub;
      op[j] = ((unsigned long long)su << 32) | (unsigned)bi[j];
    }
  } else {
    // ---- k1: Q,R projections ----
    const int blkk = blk - (8 + 512);
    const int b = blkk >> 6;
    const int n0 = (blkk & 63) << 6;
    float* sf = smem;  // [64][65]
#pragma unroll
    for (int i = 0; i < 16; ++i) {
      int lin = i * 256 + tid;
      int c = lin >> 6, nn2 = lin & 63;
      sf[c * 65 + nn2] = feat[(b * CIN + c) * NN + n0 + nn2];
    }
    __syncthreads();
    const int n = tid & 63;
    const int col0 = (tid >> 6) * 32;
    float qa[32], ra[32];
#pragma unroll
    for (int j = 0; j < 32; ++j) { qa[j] = 0.f; ra[j] = 0.f; }
    for (int c = 0; c < CIN; ++c) {
      float f = sf[c * 65 + n];
      const float4* wq = (const float4*)(w1 + c * CO + col0);
      const float4* wr = (const float4*)(w1 + (CIN + c) * CO + col0);
#pragma unroll
      for (int j = 0; j < 8; ++j) {
        float4 a = wq[j];
        float4 bb = wr[j];
        qa[4 * j + 0] = fmaf(f, a.x, qa[4 * j + 0]);
        qa[4 * j + 1] = fmaf(f, a.y, qa[4 * j + 1]);
        qa[4 * j + 2] = fmaf(f, a.z, qa[4 * j + 2]);
        qa[4 * j + 3] = fmaf(f, a.w, qa[4 * j + 3]);
        ra[4 * j + 0] = fmaf(f, bb.x, ra[4 * j + 0]);
        ra[4 * j + 1] = fmaf(f, bb.y, ra[4 * j + 1]);
        ra[4 * j + 2] = fmaf(f, bb.z, ra[4 * j + 2]);
        ra[4 * j + 3] = fmaf(f, bb.w, ra[4 * j + 3]);
      }
    }
    const float* xb = xyz + b * 3 * NN;
    const float xx = xb[n0 + n], yy = xb[NN + n0 + n], zz = xb[2 * NN + n0 + n];
#pragma unroll
    for (int j = 0; j < 32; ++j) {
      int col = col0 + j;
      float xp = fmaf(zz, w1[130 * CO + col],
                      fmaf(yy, w1[129 * CO + col], __fmul_rn(xx, w1[128 * CO + col])));
      qa[j] = qa[j] - xp + b1[col];
      ra[j] = ra[j] + xp;
    }
    float* qp = Q + (size_t)(b * NN + n0 + n) * CO + col0;
    float* rp = R + (size_t)(b * NN + n0 + n) * CO + col0;
#pragma unroll
    for (int j = 0; j < 8; ++j) {
      ((float4*)qp)[j] = make_float4(qa[4 * j], qa[4 * j + 1], qa[4 * j + 2], qa[4 * j + 3]);
      ((float4*)rp)[j] = make_float4(ra[4 * j], ra[4 * j + 1], ra[4 * j + 2], ra[4 * j + 3]);
    }
  }
}

// ---------------- k2m: fps(8) + 4-way merge->idx + BN1 partials -------------
__global__ __launch_bounds__(256) void k2m_kernel(
    const float* __restrict__ xyz, const unsigned long long* __restrict__ part,
    const float* __restrict__ Q, const float* __restrict__ R,
    int* __restrict__ idx, float* __restrict__ part1, float* __restrict__ fdist,
    int* __restrict__ fpsb) {
  __shared__ int smIdx[1024];
  __shared__ float red[512];
  const int blk = blockIdx.x;
  const int tid = threadIdx.x;
  if (blk < 8) {
    fps_chunk(xyz, fdist, fpsb, red, (int*)(red + 8), blk, 401, 501, tid);
    return;
  }
  const int blkk = blk - 8;
  const int b = blkk >> 6;
  const int n0 = (blkk & 63) * 64;
  // phase A: 4-way merge of sorted 16-lists (u64 keys unique -> no ties)
  if (tid < 64) {
    const int row = n0 + tid;
    const unsigned long long* lp = part + (size_t)(b * NN + row) * 64;
    unsigned long long h[4];
    int pos[4];
#pragma unroll
    for (int t = 0; t < 4; ++t) { pos[t] = 0; h[t] = lp[t * 16]; }
    int* op = idx + (b * NN + row) * KNb;
#pragma unroll
    for (int o = 0; o < 16; ++o) {
      unsigned long long best = h[0];
      int bt = 0;
      if (h[1] < best) { best = h[1]; bt = 1; }
      if (h[2] < best) { best = h[2]; bt = 2; }
      if (h[3] < best) { best = h[3]; bt = 3; }
      int m = (int)(unsigned)(best & 0xFFFFFFFFull);
      smIdx[tid * 16 + o] = m;
      op[o] = m;
      pos[bt]++;
      h[bt] = (pos[bt] < 16) ? lp[bt * 16 + pos[bt]] : ~0ull;
    }
  }
  __syncthreads();
  // phase B: BN1 stats over h1 = Q[n] + R[m]
  const int c = tid & 127;
  const int sub = tid >> 7;
  float s = 0.f, q = 0.f;
  for (int nn2 = 0; nn2 < 32; ++nn2) {
    int rl = sub * 32 + nn2;
    int n = n0 + rl;
    float qv = Q[(size_t)(b * NN + n) * CO + c];
#pragma unroll
    for (int k = 0; k < KNb; ++k) {
      int m = smIdx[rl * 16 + k];
      float v = qv + R[(size_t)(b * NN + m) * CO + c];
      s += v;
      q = fmaf(v, v, q);
    }
  }
  red[tid] = s;
  __syncthreads();
  float qsave = q;
  if (tid < 128) part1[blkk * 256 + tid] = red[tid] + red[tid + 128];
  __syncthreads();
  red[tid] = qsave;
  __syncthreads();
  if (tid < 128) part1[blkk * 256 + 128 + tid] = red[tid] + red[tid + 128];
}

// ------------------------------------------------- stats reduce -------------
template <int C>
__global__ void reduceA_t(const float* __restrict__ part, float* __restrict__ mid,
                          int nsrc) {
  // grid 64, block 2C; block i double-sums rows [i*chunk, (i+1)*chunk)
  const int i = blockIdx.x;
  const int tid = threadIdx.x;
  const int chunk = nsrc >> 6;
  double s = 0.0;
  const float* p = part + (size_t)i * chunk * 2 * C + tid;
  for (int k = 0; k < chunk; ++k) s += (double)p[(size_t)k * 2 * C];
  mid[i * 2 * C + tid] = (float)s;
}

template <int C>
__global__ void reduce_stats_t(const float* __restrict__ part, int nblk,
                               const float* __restrict__ gamma,
                               const float* __restrict__ beta, float cnt,
                               float* __restrict__ scale, float* __restrict__ shift) {
  __shared__ double redS[8 * C];
  __shared__ double redQ[8 * C];
  const int tid = threadIdx.x;
  const int c = tid % C;
  const int sub = tid / C;
  double s = 0.0, q = 0.0;
  for (int i = sub; i < nblk; i += 8) {
    s += (double)part[i * 2 * C + c];
    q += (double)part[i * 2 * C + C + c];
  }
  redS[sub * C + c] = s;
  redQ[sub * C + c] = q;
  __syncthreads();
  if (tid < C) {
    double ss = 0.0, qq = 0.0;
#pragma unroll
    for (int k = 0; k < 8; ++k) { ss += redS[k * C + tid]; qq += redQ[k * C + tid]; }
    double mean = ss / (double)cnt;
    double var = qq / (double)cnt - mean * mean;
    float inv = 1.0f / sqrtf((float)var + 1e-5f);
    float sc = gamma[tid] * inv;
    scale[tid] = sc;
    shift[tid] = fmaf(-(float)mean, sc, beta[tid]);
  }
}

// ------------------------------------------------- K3: layer2 GEMM ----------
template <bool STOREH2>
__global__ __launch_bounds__(256) void k3_mm2(const float* __restrict__ Q,
                                              const float* __restrict__ R,
                                              const int* __restrict__ idx,
                                              const float* __restrict__ w2,
                                              const float* __restrict__ b2,
                                              const float* __restrict__ stats,
                                              float* __restrict__ h2,
                                              float* __restrict__ part2,
                                              const float* __restrict__ xyz,
                                              float* __restrict__ fdist,
                                              int* __restrict__ fpsb) {
  __shared__ float sE[64 * 132];
  const int tid = threadIdx.x;
  if (blockIdx.x < 8) {
    fps_chunk(xyz, fdist, fpsb, sE, (int*)(sE + 8), blockIdx.x, 501, 801, tid);
    return;
  }
  const int blk = blockIdx.x - 8;
  const int b = blk >> 10;
  const int n0 = (blk & 1023) * 4;
  const int rowbase = blk * 64;
  const float* scale1 = stats;
  const float* shift1 = stats + 128;
  {
    const int r = tid >> 2, c0 = (tid & 3) * 32;
    const int np2 = r >> 4, k = r & 15;
    const int n = n0 + np2;
    const int m = idx[(b * NN + n) * KNb + k];
    const float4* qp = (const float4*)(Q + (size_t)(b * NN + n) * CO + c0);
    const float4* rp = (const float4*)(R + (size_t)(b * NN + m) * CO + c0);
    const float4* s4p = (const float4*)(scale1 + c0);
    const float4* h4p = (const float4*)(shift1 + c0);
    float* se = sE + r * 132 + c0;
#pragma unroll
    for (int j = 0; j < 8; ++j) {
      float4 a = qp[j];
      float4 bb = rp[j];
      float4 v = make_float4(a.x + bb.x, a.y + bb.y, a.z + bb.z, a.w + bb.w);
      ((float4*)se)[j] = bnrelu4(v, s4p[j], h4p[j]);
    }
  }
  __syncthreads();
  const int g = tid & 15;
  const int col0 = (tid >> 4) * 8;
  float acc[4][8];
#pragma unroll
  for (int i = 0; i < 4; ++i)
#pragma unroll
    for (int j = 0; j < 8; ++j) acc[i][j] = 0.f;
#pragma unroll 2
  for (int c = 0; c < CO; ++c) {
    float ev[4];
    ev[0] = sE[g * 132 + c];
    ev[1] = sE[(g + 16) * 132 + c];
    ev[2] = sE[(g + 32) * 132 + c];
    ev[3] = sE[(g + 48) * 132 + c];
    const float4 wa = *(const float4*)(w2 + c * CO + col0);
    const float4 wb = *(const float4*)(w2 + c * CO + col0 + 4);
    const float wv[8] = {wa.x, wa.y, wa.z, wa.w, wb.x, wb.y, wb.z, wb.w};
#pragma unroll
    for (int i = 0; i < 4; ++i)
#pragma unroll
      for (int j = 0; j < 8; ++j) acc[i][j] = fmaf(ev[i], wv[j], acc[i][j]);
  }
  const float4 bA = *(const float4*)(b2 + col0);
  const float4 bB = *(const float4*)(b2 + col0 + 4);
  const float bv[8] = {bA.x, bA.y, bA.z, bA.w, bB.x, bB.y, bB.z, bB.w};
  float bsum[8], bsq[8];
#pragma unroll
  for (int j = 0; j < 8; ++j) { bsum[j] = 0.f; bsq[j] = 0.f; }
#pragma unroll
  for (int i = 0; i < 4; ++i) {
    float v[8];
#pragma unroll
    for (int j = 0; j < 8; ++j) {
      v[j] = acc[i][j] + bv[j];
      bsum[j] += v[j];
      bsq[j] = fmaf(v[j], v[j], bsq[j]);
    }
    if constexpr (STOREH2) {
      float* hp = h2 + (size_t)(rowbase + g + 16 * i) * CO + col0;
      *(float4*)(hp) = make_float4(v[0], v[1], v[2], v[3]);
      *(float4*)(hp + 4) = make_float4(v[4], v[5], v[6], v[7]);
    }
  }
  __syncthreads();
  float* sS = sE;
  float* sQ2 = sE + 2048;
#pragma unroll
  for (int j = 0; j < 8; ++j) {
    sS[g * 128 + col0 + j] = bsum[j];
    sQ2[g * 128 + col0 + j] = bsq[j];
  }
  __syncthreads();
  if (tid < 128) {
    float ss = 0.f, qq = 0.f;
#pragma unroll
    for (int gg = 0; gg < 16; ++gg) {
      ss += sS[gg * 128 + tid];
      qq += sQ2[gg * 128 + tid];
    }
    part2[blk * 256 + tid] = ss;
    part2[blk * 256 + 128 + tid] = qq;
  }
}

// ------------------------------------------------- e2 tile builder ----------
template <bool RECOMP>
__device__ __forceinline__ void build_e2_tile(
    float* sE, const int b, const int n0, const int rowbase, const int tid,
    const float* __restrict__ Q, const float* __restrict__ R,
    const int* __restrict__ idx, const float* __restrict__ w2,
    const float* __restrict__ b2, const float* __restrict__ h2,
    const float* __restrict__ stats) {
  const float* sc2 = stats + 256;
  const float* sh2 = stats + 384;
  const int r = tid >> 2, c0 = (tid & 3) * 32;
  if constexpr (!RECOMP) {
    const float4* hp = (const float4*)(h2 + (size_t)(rowbase + r) * CO + c0);
    const float4* s4p = (const float4*)(sc2 + c0);
    const float4* h4p = (const float4*)(sh2 + c0);
    float* se = sE + r * 132 + c0;
#pragma unroll
    for (int j = 0; j < 8; ++j) ((float4*)se)[j] = bnrelu4(hp[j], s4p[j], h4p[j]);
    __syncthreads();
  } else {
    const float* sc1 = stats;
    const float* sh1 = stats + 128;
    {
      const int np2 = r >> 4, k = r & 15;
      const int n = n0 + np2;
      const int m = idx[(b * NN + n) * KNb + k];
      const float4* qp = (const float4*)(Q + (size_t)(b * NN + n) * CO + c0);
      const float4* rp = (const float4*)(R + (size_t)(b * NN + m) * CO + c0);
      const float4* s4p = (const float4*)(sc1 + c0);
      const float4* h4p = (const float4*)(sh1 + c0);
      float* se = sE + r * 132 + c0;
#pragma unroll
      for (int j = 0; j < 8; ++j) {
        float4 a = qp[j];
        float4 bb = rp[j];
        float4 v = make_float4(a.x + bb.x, a.y + bb.y, a.z + bb.z, a.w + bb.w);
        ((float4*)se)[j] = bnrelu4(v, s4p[j], h4p[j]);
      }
    }
    __syncthreads();
    const int g = tid & 15, col0 = (tid >> 4) * 8;
    float acc[4][8];
#pragma unroll
    for (int i = 0; i < 4; ++i)
#pragma unroll
      for (int j = 0; j < 8; ++j) acc[i][j] = 0.f;
#pragma unroll 2
    for (int c = 0; c < CO; ++c) {
      float ev[4];
      ev[0] = sE[g * 132 + c];
      ev[1] = sE[(g + 16) * 132 + c];
      ev[2] = sE[(g + 32) * 132 + c];
      ev[3] = sE[(g + 48) * 132 + c];
      const float4 wa = *(const float4*)(w2 + c * CO + col0);
      const float4 wb = *(const float4*)(w2 + c * CO + col0 + 4);
      const float wv[8] = {wa.x, wa.y, wa.z, wa.w, wb.x, wb.y, wb.z, wb.w};
#pragma unroll
      for (int i = 0; i < 4; ++i)
#pragma unroll
        for (int j = 0; j < 8; ++j) acc[i][j] = fmaf(ev[i], wv[j], acc[i][j]);
    }
    __syncthreads();  // all reads of e1 done before overwrite
    const float4 bA = *(const float4*)(b2 + col0);
    const float4 bB = *(const float4*)(b2 + col0 + 4);
    const float4 sA4 = *(const float4*)(sc2 + col0);
    const float4 sB4 = *(const float4*)(sc2 + col0 + 4);
    const float4 hA4 = *(const float4*)(sh2 + col0);
    const float4 hB4 = *(const float4*)(sh2 + col0 + 4);
#pragma unroll
    for (int i = 0; i < 4; ++i) {
      float4 v0 = make_float4(acc[i][0] + bA.x, acc[i][1] + bA.y,
                              acc[i][2] + bA.z, acc[i][3] + bA.w);
      float4 v1 = make_float4(acc[i][4] + bB.x, acc[i][5] + bB.y,
                              acc[i][6] + bB.z, acc[i][7] + bB.w);
      float* se = sE + (g + 16 * i) * 132 + col0;
      *(float4*)se = bnrelu4(v0, sA4, hA4);
      *(float4*)(se + 4) = bnrelu4(v1, sB4, hB4);
    }
    __syncthreads();
  }
}

// ------------------------------------------------- K4: attention MLP1 -------
template <bool RECOMP, bool STORET>
__global__ __launch_bounds__(256) void k4_attn1(
    const float* __restrict__ Q, const float* __restrict__ R,
    const int* __restrict__ idx, const float* __restrict__ w2,
    const float* __restrict__ b2, const float* __restrict__ h2,
    const float* __restrict__ wa1, const float* __restrict__ ba1,
    const float* __restrict__ stats, float* __restrict__ t,
    float* __restrict__ parta, const float* __restrict__ xyz,
    float* __restrict__ fdist, int* __restrict__ fpsb) {
  __shared__ float sE[64 * 132];
  const int tid = threadIdx.x;
  if (blockIdx.x < 8) {
    fps_chunk(xyz, fdist, fpsb, sE, (int*)(sE + 8), blockIdx.x, 801, 951, tid);
    return;
  }
  const int blk = blockIdx.x - 8;
  const int b = blk >> 10;
  const int n0 = (blk & 1023) * 4;
  const int rowbase = blk * 64;
  build_e2_tile<RECOMP>(sE, b, n0, rowbase, tid, Q, R, idx, w2, b2, h2, stats);
  const int g = tid & 15;
  const int col0 = (tid >> 4) * 2;
  float a0 = 0.f, a1 = 0.f, a2 = 0.f, a3 = 0.f, b0 = 0.f, b1v = 0.f, b2v = 0.f, b3 = 0.f;
#pragma unroll 4
  for (int c = 0; c < CO; ++c) {
    float e0 = sE[g * 132 + c];
    float e1 = sE[(g + 16) * 132 + c];
    float e2 = sE[(g + 32) * 132 + c];
    float e3 = sE[(g + 48) * 132 + c];
    float2 w = *(const float2*)(wa1 + c * 32 + col0);
    a0 = fmaf(e0, w.x, a0); b0 = fmaf(e0, w.y, b0);
    a1 = fmaf(e1, w.x, a1); b1v = fmaf(e1, w.y, b1v);
    a2 = fmaf(e2, w.x, a2); b2v = fmaf(e2, w.y, b2v);
    a3 = fmaf(e3, w.x, a3); b3 = fmaf(e3, w.y, b3);
  }
  const float2 bb = *(const float2*)(ba1 + col0);
  float s2[2] = {0.f, 0.f}, q2[2] = {0.f, 0.f};
  float va[4] = {a0 + bb.x, a1 + bb.x, a2 + bb.x, a3 + bb.x};
  float vb[4] = {b0 + bb.y, b1v + bb.y, b2v + bb.y, b3 + bb.y};
#pragma unroll
  for (int i = 0; i < 4; ++i) {
    if constexpr (STORET) {
      *(float2*)(t + (size_t)(rowbase + g + 16 * i) * 32 + col0) = make_float2(va[i], vb[i]);
    }
    s2[0] += va[i]; q2[0] = fmaf(va[i], va[i], q2[0]);
    s2[1] += vb[i]; q2[1] = fmaf(vb[i], vb[i], q2[1]);
  }
  __syncthreads();
  float* sS = sE;
  sS[g * 32 + col0] = s2[0];
  sS[g * 32 + col0 + 1] = s2[1];
  sS[512 + g * 32 + col0] = q2[0];
  sS[512 + g * 32 + col0 + 1] = q2[1];
  __syncthreads();
  if (tid < 32) {
    float ss = 0.f, qq = 0.f;
#pragma unroll
    for (int gg = 0; gg < 16; ++gg) {
      ss += sS[gg * 32 + tid];
      qq += sS[512 + gg * 32 + tid];
    }
    parta[blk * 64 + tid] = ss;
    parta[blk * 64 + 32 + tid] = qq;
  }
}

// ------------------------------------------------- K5: softmax + out --------
template <bool RECOMP, bool LOADT>
__global__ __launch_bounds__(256) void k5_out(
    const float* __restrict__ Q, const float* __restrict__ R,
    const int* __restrict__ idx, const float* __restrict__ w2,
    const float* __restrict__ b2, const float* __restrict__ h2,
    const float* __restrict__ t, const float* __restrict__ wa1,
    const float* __restrict__ ba1, const float* __restrict__ wa2,
    const float* __restrict__ ba2, const float* __restrict__ stats,
    float* __restrict__ out, const float* __restrict__ xyz,
    float* __restrict__ fdist, int* __restrict__ fpsb) {
  __shared__ float sE[64 * 132];
  __shared__ float sA[64];
  const int tid = threadIdx.x;
  if (blockIdx.x < 8) {
    fps_chunk(xyz, fdist, fpsb, sE, (int*)(sE + 8), blockIdx.x, 951, 1024, tid);
    return;
  }
  const int blk = blockIdx.x - 8;
  const int b = blk >> 10;
  const int n0 = (blk & 1023) * 4;
  const int rowbase = blk * 64;
  build_e2_tile<RECOMP>(sE, b, n0, rowbase, tid, Q, R, idx, w2, b2, h2, stats);
  const float* sna = stats + 512;
  const float* sha = stats + 544;
  {
    const int r = tid >> 2, q = tid & 3;
    float a2 = 0.f;
    if constexpr (LOADT) {
      const float* tp = t + (size_t)(rowbase + r) * 32 + q * 8;
#pragma unroll
      for (int j = 0; j < 8; j += 4) {
        float4 tv = *(const float4*)(tp + j);
        float4 s4 = *(const float4*)(sna + q * 8 + j);
        float4 h4 = *(const float4*)(sha + q * 8 + j);
        a2 = fmaf(fmaxf(0.f, fmaf(tv.x, s4.x, h4.x)), wa2[q * 8 + j], a2);
        a2 = fmaf(fmaxf(0.f, fmaf(tv.y, s4.y, h4.y)), wa2[q * 8 + j + 1], a2);
        a2 = fmaf(fmaxf(0.f, fmaf(tv.z, s4.z, h4.z)), wa2[q * 8 + j + 2], a2);
        a2 = fmaf(fmaxf(0.f, fmaf(tv.w, s4.w, h4.w)), wa2[q * 8 + j + 3], a2);
      }
    } else {
      float tj[8];
      const float4 bA = *(const float4*)(ba1 + q * 8);
      const float4 bB = *(const float4*)(ba1 + q * 8 + 4);
      tj[0] = bA.x; tj[1] = bA.y; tj[2] = bA.z; tj[3] = bA.w;
      tj[4] = bB.x; tj[5] = bB.y; tj[6] = bB.z; tj[7] = bB.w;
      for (int c = 0; c < CO; ++c) {
        float e = sE[r * 132 + c];
        const float4 wA = *(const float4*)(wa1 + c * 32 + q * 8);
        const float4 wB = *(const float4*)(wa1 + c * 32 + q * 8 + 4);
        tj[0] = fmaf(e, wA.x, tj[0]); tj[1] = fmaf(e, wA.y, tj[1]);
        tj[2] = fmaf(e, wA.z, tj[2]); tj[3] = fmaf(e, wA.w, tj[3]);
        tj[4] = fmaf(e, wB.x, tj[4]); tj[5] = fmaf(e, wB.y, tj[5]);
        tj[6] = fmaf(e, wB.z, tj[6]); tj[7] = fmaf(e, wB.w, tj[7]);
      }
#pragma unroll
      for (int j = 0; j < 8; ++j)
        a2 = fmaf(fmaxf(0.f, fmaf(tj[j], sna[q * 8 + j], sha[q * 8 + j])),
                  wa2[q * 8 + j], a2);
    }
    a2 += __shfl_xor(a2, 1);
    a2 += __shfl_xor(a2, 2);
    a2 += ba2[0];
    float m = a2;
#pragma unroll
    for (int off = 4; off < 64; off <<= 1) m = fmaxf(m, __shfl_xor(m, off));
    float p = expf(a2 - m);
    float s = p;
#pragma unroll
    for (int off = 4; off < 64; off <<= 1) s += __shfl_xor(s, off);
    if (q == 0) sA[r] = p / s;
  }
  __syncthreads();
  const int np2 = tid >> 6;
  const int cg = tid & 63;
  const int c0 = cg * 2;
  float o0 = 0.f, o1 = 0.f;
#pragma unroll
  for (int k = 0; k < 16; ++k) {
    float aw = sA[np2 * 16 + k];
    o0 = fmaf(aw, sE[(np2 * 16 + k) * 132 + c0], o0);
    o1 = fmaf(aw, sE[(np2 * 16 + k) * 132 + c0 + 1], o1);
  }
  float* op = out + (size_t)(b * NN + n0 + np2) * CO + c0;
  *(float2*)op = make_float2(o0, o1);
}

// ------------------------------------------------- K6: gather stats ---------
__global__ __launch_bounds__(256) void k6_gstats(const float* __restrict__ out,
                                                 const int* __restrict__ fps,
                                                 float* __restrict__ partf) {
  __shared__ float red[512];
  const int blk = blockIdx.x;
  const int tid = threadIdx.x;
  const int c = tid & 127;
  const int half = tid >> 7;
  float s = 0.f, q = 0.f;
  for (int i = 0; i < 128; ++i) {
    int row = blk * 256 + half * 128 + i;
    int b = row >> 10, p = row & 1023;
    int fi = fps[b * NP + p];
    float v = out[(size_t)(b * NN + fi) * CO + c];
    s += v;
    q = fmaf(v, v, q);
  }
  red[tid] = s;
  red[256 + tid] = q;
  __syncthreads();
  if (tid < 128) {
    partf[blk * 256 + tid] = red[tid] + red[tid + 128];
    partf[blk * 256 + 128 + tid] = red[256 + tid] + red[256 + tid + 128];
  }
}

// ------------------------------------------------- K7: final outputs --------
__global__ __launch_bounds__(256) void k7_final(const float* __restrict__ xyz,
                                                const float* __restrict__ out,
                                                const int* __restrict__ fps,
                                                const float* __restrict__ stats,
                                                float* __restrict__ dout) {
  const int gid = blockIdx.x * 256 + threadIdx.x;
  const int NX = BB * 3 * NP;  // 24576
  if (gid < NX) {
    int b = gid / 3072;
    int rem = gid - b * 3072;
    int d = rem >> 10, p = rem & 1023;
    int fi = fps[b * NP + p];
    dout[gid] = xyz[(b * 3 + d) * NN + fi];
  } else {
    int h = gid - NX;
    if (h < BB * CO * NP) {
      int b = h >> 17;
      int c = (h >> 10) & 127;
      int p = h & 1023;
      int fi = fps[b * NP + p];
      float v = out[(size_t)(b * NN + fi) * CO + c];
      dout[gid] = fmaf(v, stats[576 + c], stats[704 + c]);
    }
  }
}

// ---------------------------------------------------------------------------
extern "C" void kernel_launch(void* const* d_in, const int* in_sizes, int n_in,
                              void* d_out, int out_size, void* d_ws, size_t ws_size,
                              hipStream_t stream) {
  const float* xyz = (const float*)d_in[0];
  const float* feat = (const float*)d_in[1];
  const float* w1 = (const float*)d_in[2];
  const float* b1 = (const float*)d_in[3];
  const float* g1 = (const float*)d_in[4];
  const float* be1 = (const float*)d_in[5];
  const float* w2 = (const float*)d_in[6];
  const float* b2 = (const float*)d_in[7];
  const float* g2 = (const float*)d_in[8];
  const float* be2 = (const float*)d_in[9];
  const float* wa1 = (const float*)d_in[10];
  const float* ba1 = (const float*)d_in[11];
  const float* ga = (const float*)d_in[12];
  const float* bea = (const float*)d_in[13];
  const float* wa2 = (const float*)d_in[14];
  const float* ba2 = (const float*)d_in[15];
  const float* gf = (const float*)d_in[16];
  const float* bf = (const float*)d_in[17];
  float* outp = (float*)d_out;

  char* ws = (char*)d_ws;
  size_t off = 0;
  auto alloc = [&](size_t bytes) -> void* {
    void* p = ws + off;
    off = (off + bytes + 255) & ~(size_t)255;
    return p;
  };
  unsigned long long* part = (unsigned long long*)alloc((size_t)BB * NN * 64 * 8);  // 16.8 MB
  int* idx = (int*)alloc((size_t)BB * NN * KNb * 4);
  int* fpsb = (int*)alloc((size_t)BB * NP * 4);
  float* fdist = (float*)alloc((size_t)BB * NN * 4);  // FPS state
  float* Q = (float*)alloc((size_t)BB * NN * CO * 4);
  float* R = (float*)alloc((size_t)BB * NN * CO * 4);
  float* ob = (float*)alloc((size_t)BB * NN * CO * 4);
  float* part1 = (float*)alloc((size_t)512 * 256 * 4);
  float* part2 = (float*)alloc((size_t)8192 * 256 * 4);
  float* parta = (float*)alloc((size_t)8192 * 64 * 4);
  float* partf = (float*)alloc((size_t)32 * 256 * 4);
  float* mid2 = (float*)alloc((size_t)64 * 256 * 4);
  float* mida = (float*)alloc((size_t)64 * 64 * 4);
  float* stats = (float*)alloc((size_t)1024 * 4);
  const size_t h2_bytes = (size_t)BB * NN * KNb * CO * 4;  // 268 MB
  const size_t t_bytes = (size_t)BB * NN * KNb * 32 * 4;   // 67 MB
  const bool has_h2 = (off + h2_bytes + 256 <= ws_size);
  float* h2 = has_h2 ? (float*)alloc(h2_bytes) : nullptr;
  const bool has_t = (off + t_bytes + 256 <= ws_size);
  float* tb = has_t ? (float*)alloc(t_bytes) : nullptr;

  const float CNT1 = (float)(BB * NN * KNb);
  front_kernel<<<8 + 512 + 512, 256, 0, stream>>>(xyz, feat, w1, b1, part, Q, R, fdist, fpsb);
  k2m_kernel<<<8 + 512, 256, 0, stream>>>(xyz, part, Q, R, idx, part1, fdist, fpsb);
  reduce_stats_t<128><<<1, 1024, 0, stream>>>(part1, 512, g1, be1, CNT1, stats, stats + 128);
  if (has_h2)
    k3_mm2<true><<<8 + 8192, 256, 0, stream>>>(Q, R, idx, w2, b2, stats, h2, part2, xyz, fdist, fpsb);
  else
    k3_mm2<false><<<8 + 8192, 256, 0, stream>>>(Q, R, idx, w2, b2, stats, h2, part2, xyz, fdist, fpsb);
  reduceA_t<128><<<64, 256, 0, stream>>>(part2, mid2, 8192);
  reduce_stats_t<128><<<1, 1024, 0, stream>>>(mid2, 64, g2, be2, CNT1, stats + 256, stats + 384);
  if (has_h2 && has_t)
    k4_attn1<false, true><<<8 + 8192, 256, 0, stream>>>(Q, R, idx, w2, b2, h2, wa1, ba1, stats, tb, parta, xyz, fdist, fpsb);
  else if (has_h2)
    k4_attn1<false, false><<<8 + 8192, 256, 0, stream>>>(Q, R, idx, w2, b2, h2, wa1, ba1, stats, tb, parta, xyz, fdist, fpsb);
  else if (has_t)
    k4_attn1<true, true><<<8 + 8192, 256, 0, stream>>>(Q, R, idx, w2, b2, h2, wa1, ba1, stats, tb, parta, xyz, fdist, fpsb);
  else
    k4_attn1<true, false><<<8 + 8192, 256, 0, stream>>>(Q, R, idx, w2, b2, h2, wa1, ba1, stats, tb, parta, xyz, fdist, fpsb);
  reduceA_t<32><<<64, 64, 0, stream>>>(parta, mida, 8192);
  reduce_stats_t<32><<<1, 256, 0, stream>>>(mida, 64, ga, bea, CNT1, stats + 512, stats + 544);
  if (has_h2 && has_t)
    k5_out<false, true><<<8 + 8192, 256, 0, stream>>>(Q, R, idx, w2, b2, h2, tb, wa1, ba1, wa2, ba2, stats, ob, xyz, fdist, fpsb);
  else if (has_h2)
    k5_out<false, false><<<8 + 8192, 256, 0, stream>>>(Q, R, idx, w2, b2, h2, tb, wa1, ba1, wa2, ba2, stats, ob, xyz, fdist, fpsb);
  else if (has_t)
    k5_out<true, true><<<8 + 8192, 256, 0, stream>>>(Q, R, idx, w2, b2, h2, tb, wa1, ba1, wa2, ba2, stats, ob, xyz, fdist, fpsb);
  else
    k5_out<true, false><<<8 + 8192, 256, 0, stream>>>(Q, R, idx, w2, b2, h2, tb, wa1, ba1, wa2, ba2, stats, ob, xyz, fdist, fpsb);
  k6_gstats<<<32, 256, 0, stream>>>(ob, fpsb, partf);
  reduce_stats_t<128><<<1, 1024, 0, stream>>>(partf, 32, gf, bf, (float)(BB * NP), stats + 576, stats + 704);
  k7_final<<<4192, 256, 0, stream>>>(xyz, ob, fpsb, stats, outp);
}

// Round 9
// 1437.073 us; speedup vs baseline: 2.6151x; 1.3246x over previous
//
#include <hip/hip_runtime.h>
#include <hip/hip_fp16.h>
#include <math.h>

// ---------------------------------------------------------------------------
// SetAbstraction (PointNet++-style) for MI355X.
//   front : fps chunk (8) + KNN 1024-cand substream top-16 (512) + k1 Q/R (512)
//   k2m   : fps chunk + 4-way merge -> idx + BN1 partials
//   k3    : fps chunk + e1=relu(bn1(h1)); h2=e1@w2+b2; BN2 partials;
//           store h2 as fp16 (134MB, adaptive - single GEMM pass if it fits)
//   k4    : fps chunk + e2 (load h2e or recompute); t=e2@wa1+ba1 (fp16 store);
//           BNa partials
//   k5    : fps chunk + e2; softmax_K from fp16 t; out=sum_k a*e2
//   k6/k7 : gather stats + final outputs
// ---------------------------------------------------------------------------

#define BB 8
#define NN 4096
#define CIN 64
#define CO 128
#define KNb 16
#define NP 1024

__device__ __forceinline__ float4 bnrelu4(float4 v, float4 s, float4 h) {
  float4 e;
  e.x = fmaxf(0.f, fmaf(v.x, s.x, h.x));
  e.y = fmaxf(0.f, fmaf(v.y, s.y, h.y));
  e.z = fmaxf(0.f, fmaf(v.z, s.z, h.z));
  e.w = fmaxf(0.f, fmaf(v.w, s.w, h.w));
  return e;
}

// ---------------- DPP wave(64) reductions: result broadcast via readlane ----
__device__ __forceinline__ float wave_fmax_bcast(float x) {
#define DPPF(ctrl, rmask)                                                        \
  {                                                                              \
    int t_ = __builtin_amdgcn_update_dpp(0xff800000, __float_as_int(x), ctrl,    \
                                         rmask, 0xf, false);                     \
    x = fmaxf(x, __int_as_float(t_));                                            \
  }
  DPPF(0x111, 0xf) DPPF(0x112, 0xf) DPPF(0x114, 0xf) DPPF(0x118, 0xf)
  DPPF(0x142, 0xa) DPPF(0x143, 0xc)
#undef DPPF
  return __int_as_float(__builtin_amdgcn_readlane(__float_as_int(x), 63));
}
__device__ __forceinline__ unsigned wave_umin_bcast(unsigned x) {
#define DPPU(ctrl, rmask)                                                        \
  {                                                                              \
    unsigned t_ = (unsigned)__builtin_amdgcn_update_dpp(-1, (int)x, ctrl, rmask, \
                                                        0xf, false);             \
    x = (t_ < x) ? t_ : x;                                                       \
  }
  DPPU(0x111, 0xf) DPPU(0x112, 0xf) DPPU(0x114, 0xf) DPPU(0x118, 0xf)
  DPPU(0x142, 0xa) DPPU(0x143, 0xc)
#undef DPPU
  return (unsigned)__builtin_amdgcn_readlane((int)x, 63);
}

// ---------------- FPS chunk: iters [s0,s1), state in fdist / fps[] ----------
__device__ void fps_chunk(const float* __restrict__ xyz, float* __restrict__ fdist,
                          int* __restrict__ fpsb, float* slotF, int* slotP,
                          int b, int s0, int s1, int tid) {
  const float* xb = xyz + b * 3 * NN;
  float px[16], py[16], pz[16], dist[16];
#pragma unroll
  for (int i = 0; i < 16; ++i) {
    int p = i * 256 + tid;
    px[i] = xb[p]; py[i] = xb[NN + p]; pz[i] = xb[2 * NN + p];
  }
  int far;
  if (s0 == 1) {
#pragma unroll
    for (int i = 0; i < 16; ++i) dist[i] = 1e10f;
    far = 0;
    if (tid == 0) fpsb[b * NP] = 0;
  } else {
#pragma unroll
    for (int i = 0; i < 16; ++i) dist[i] = fdist[b * NN + i * 256 + tid];
    far = fpsb[b * NP + s0 - 1];
  }
  for (int s = s0; s < s1; ++s) {
    const float cx = xb[far], cy = xb[NN + far], cz = xb[2 * NN + far];
    float lm = -3.4e38f;
    int lp = 0x7FFFFFFF;
#pragma unroll
    for (int i = 0; i < 16; ++i) {
      float dx = __fsub_rn(px[i], cx);
      float dy = __fsub_rn(py[i], cy);
      float dz = __fsub_rn(pz[i], cz);
      float d = __fadd_rn(__fadd_rn(__fmul_rn(dx, dx), __fmul_rn(dy, dy)),
                          __fmul_rn(dz, dz));
      float nd = fminf(dist[i], d);
      dist[i] = nd;
      bool gt = nd > lm;  // strict >: earliest (lowest) index kept
      lm = gt ? nd : lm;
      lp = gt ? (i * 256 + tid) : lp;
    }
    float wm = wave_fmax_bcast(lm);
    unsigned cand = (lm == wm) ? (unsigned)lp : 0xFFFFFFFFu;
    unsigned wp = wave_umin_bcast(cand);
    const int w = tid >> 6, par = (s & 1) * 4;
    if ((tid & 63) == 0) { slotF[par + w] = wm; slotP[par + w] = (int)wp; }
    __syncthreads();
    float bf = slotF[par]; int bp = slotP[par];
#pragma unroll
    for (int w2 = 1; w2 < 4; ++w2) {
      float f = slotF[par + w2]; int p = slotP[par + w2];
      if (f > bf || (f == bf && p < bp)) { bf = f; bp = p; }
    }
    far = bp;
    if (tid == 0) fpsb[b * NP + s] = far;
  }
#pragma unroll
  for (int i = 0; i < 16; ++i) fdist[b * NN + i * 256 + tid] = dist[i];
}

// ---------------- front: fps(8) + knn partial(512) + k1(512) ----------------
__global__ __launch_bounds__(256) void front_kernel(
    const float* __restrict__ xyz, const float* __restrict__ feat,
    const float* __restrict__ w1, const float* __restrict__ b1,
    unsigned long long* __restrict__ part, float* __restrict__ Q,
    float* __restrict__ R, float* __restrict__ fdist, int* __restrict__ fpsb) {
  __shared__ __align__(16) float smem[4224];  // 16.9 KB
  const int blk = blockIdx.x;
  const int tid = threadIdx.x;
  if (blk < 8) {
    fps_chunk(xyz, fdist, fpsb, smem, (int*)(smem + 8), blk, 1, 401, tid);
  } else if (blk < 8 + 512) {
    // ---- KNN partial: 256 rows/block, 1024-cand substream, branchless ----
    const int blkk = blk - 8;
    const int b = blkk >> 6;
    const int rem = blkk & 63;
    const int n0 = (rem >> 2) << 8;  // row tile base (16 tiles of 256)
    const int m0 = (rem & 3) << 10;  // candidate range base (4 subs of 1024)
    const float* xb = xyz + b * 3 * NN;
    float4* cand = (float4*)smem;    // 1024 float4 = 16 KB
#pragma unroll
    for (int i = 0; i < 4; ++i) {
      int local = i * 256 + tid;
      int m = m0 + local;
      float x = xb[m], y = xb[NN + m], z = xb[2 * NN + m];
      float sq = __fadd_rn(__fadd_rn(__fmul_rn(x, x), __fmul_rn(y, y)),
                           __fmul_rn(z, z));
      cand[local] = make_float4(x, y, z, sq);
    }
    const int n = n0 + tid;
    const float xn = xb[n], yn = xb[NN + n], zn = xb[2 * NN + n];
    const float sqn = __fadd_rn(__fadd_rn(__fmul_rn(xn, xn), __fmul_rn(yn, yn)),
                                __fmul_rn(zn, zn));
    float bd[16];
    int bi[16];
#pragma unroll
    for (int j = 0; j < 16; ++j) { bd[j] = 3.4e38f; bi[j] = 0; }
    __syncthreads();
    for (int mm = 0; mm < 1024; ++mm) {
      float4 pm = cand[mm];
      float dot = fmaf(zn, pm.z, fmaf(yn, pm.y, __fmul_rn(xn, pm.x)));
      float d = __fsub_rn(__fadd_rn(sqn, pm.w), __fmul_rn(2.0f, dot));
      const int ci = m0 + mm;
      // branchless parallel-rank insertion (strict <: ties keep lower index)
      bool c[16];
#pragma unroll
      for (int j = 0; j < 16; ++j) c[j] = d < bd[j];
#pragma unroll
      for (int j = 15; j >= 1; --j) {
        float td = c[j - 1] ? bd[j - 1] : d;
        int ti = c[j - 1] ? bi[j - 1] : ci;
        bd[j] = c[j] ? td : bd[j];
        bi[j] = c[j] ? ti : bi[j];
      }
      bd[0] = c[0] ? d : bd[0];
      bi[0] = c[0] ? ci : bi[0];
    }
    // pack sortable u64 keys (d asc, idx asc) and store
    unsigned long long* op = part + (size_t)(b * NN + n) * 64 + (rem & 3) * 16;
#pragma unroll
    for (int j = 0; j < 16; ++j) {
      unsigned ub = __float_as_uint(bd[j]);
      unsigned su = (bd[j] >= 0.f) ? (ub | 0x80000000u) : ~ub;
      op[j] = ((unsigned long long)su << 32) | (unsigned)bi[j];
    }
  } else {
    // ---- k1: Q,R projections ----
    const int blkk = blk - (8 + 512);
    const int b = blkk >> 6;
    const int n0 = (blkk & 63) << 6;
    float* sf = smem;  // [64][65]
#pragma unroll
    for (int i = 0; i < 16; ++i) {
      int lin = i * 256 + tid;
      int c = lin >> 6, nn2 = lin & 63;
      sf[c * 65 + nn2] = feat[(b * CIN + c) * NN + n0 + nn2];
    }
    __syncthreads();
    const int n = tid & 63;
    const int col0 = (tid >> 6) * 32;
    float qa[32], ra[32];
#pragma unroll
    for (int j = 0; j < 32; ++j) { qa[j] = 0.f; ra[j] = 0.f; }
    for (int c = 0; c < CIN; ++c) {
      float f = sf[c * 65 + n];
      const float4* wq = (const float4*)(w1 + c * CO + col0);
      const float4* wr = (const float4*)(w1 + (CIN + c) * CO + col0);
#pragma unroll
      for (int j = 0; j < 8; ++j) {
        float4 a = wq[j];
        float4 bb = wr[j];
        qa[4 * j + 0] = fmaf(f, a.x, qa[4 * j + 0]);
        qa[4 * j + 1] = fmaf(f, a.y, qa[4 * j + 1]);
        qa[4 * j + 2] = fmaf(f, a.z, qa[4 * j + 2]);
        qa[4 * j + 3] = fmaf(f, a.w, qa[4 * j + 3]);
        ra[4 * j + 0] = fmaf(f, bb.x, ra[4 * j + 0]);
        ra[4 * j + 1] = fmaf(f, bb.y, ra[4 * j + 1]);
        ra[4 * j + 2] = fmaf(f, bb.z, ra[4 * j + 2]);
        ra[4 * j + 3] = fmaf(f, bb.w, ra[4 * j + 3]);
      }
    }
    const float* xb = xyz + b * 3 * NN;
    const float xx = xb[n0 + n], yy = xb[NN + n0 + n], zz = xb[2 * NN + n0 + n];
#pragma unroll
    for (int j = 0; j < 32; ++j) {
      int col = col0 + j;
      float xp = fmaf(zz, w1[130 * CO + col],
                      fmaf(yy, w1[129 * CO + col], __fmul_rn(xx, w1[128 * CO + col])));
      qa[j] = qa[j] - xp + b1[col];
      ra[j] = ra[j] + xp;
    }
    float* qp = Q + (size_t)(b * NN + n0 + n) * CO + col0;
    float* rp = R + (size_t)(b * NN + n0 + n) * CO + col0;
#pragma unroll
    for (int j = 0; j < 8; ++j) {
      ((float4*)qp)[j] = make_float4(qa[4 * j], qa[4 * j + 1], qa[4 * j + 2], qa[4 * j + 3]);
      ((float4*)rp)[j] = make_float4(ra[4 * j], ra[4 * j + 1], ra[4 * j + 2], ra[4 * j + 3]);
    }
  }
}

// ---------------- k2m: fps(8) + 4-way merge->idx + BN1 partials -------------
__global__ __launch_bounds__(256) void k2m_kernel(
    const float* __restrict__ xyz, const unsigned long long* __restrict__ part,
    const float* __restrict__ Q, const float* __restrict__ R,
    int* __restrict__ idx, float* __restrict__ part1, float* __restrict__ fdist,
    int* __restrict__ fpsb) {
  __shared__ int smIdx[1024];
  __shared__ float red[512];
  const int blk = blockIdx.x;
  const int tid = threadIdx.x;
  if (blk < 8) {
    fps_chunk(xyz, fdist, fpsb, red, (int*)(red + 8), blk, 401, 501, tid);
    return;
  }
  const int blkk = blk - 8;
  const int b = blkk >> 6;
  const int n0 = (blkk & 63) * 64;
  // phase A: 4-way merge of sorted 16-lists (u64 keys unique -> no ties)
  if (tid < 64) {
    const int row = n0 + tid;
    const unsigned long long* lp = part + (size_t)(b * NN + row) * 64;
    unsigned long long h[4];
    int pos[4];
#pragma unroll
    for (int t = 0; t < 4; ++t) { pos[t] = 0; h[t] = lp[t * 16]; }
    int* op = idx + (b * NN + row) * KNb;
#pragma unroll
    for (int o = 0; o < 16; ++o) {
      unsigned long long best = h[0];
      int bt = 0;
      if (h[1] < best) { best = h[1]; bt = 1; }
      if (h[2] < best) { best = h[2]; bt = 2; }
      if (h[3] < best) { best = h[3]; bt = 3; }
      int m = (int)(unsigned)(best & 0xFFFFFFFFull);
      smIdx[tid * 16 + o] = m;
      op[o] = m;
      pos[bt]++;
      h[bt] = (pos[bt] < 16) ? lp[bt * 16 + pos[bt]] : ~0ull;
    }
  }
  __syncthreads();
  // phase B: BN1 stats over h1 = Q[n] + R[m]
  const int c = tid & 127;
  const int sub = tid >> 7;
  float s = 0.f, q = 0.f;
  for (int nn2 = 0; nn2 < 32; ++nn2) {
    int rl = sub * 32 + nn2;
    int n = n0 + rl;
    float qv = Q[(size_t)(b * NN + n) * CO + c];
#pragma unroll
    for (int k = 0; k < KNb; ++k) {
      int m = smIdx[rl * 16 + k];
      float v = qv + R[(size_t)(b * NN + m) * CO + c];
      s += v;
      q = fmaf(v, v, q);
    }
  }
  red[tid] = s;
  __syncthreads();
  float qsave = q;
  if (tid < 128) part1[blkk * 256 + tid] = red[tid] + red[tid + 128];
  __syncthreads();
  red[tid] = qsave;
  __syncthreads();
  if (tid < 128) part1[blkk * 256 + 128 + tid] = red[tid] + red[tid + 128];
}

// ------------------------------------------------- stats reduce -------------
template <int C>
__global__ void reduceA_t(const float* __restrict__ part, float* __restrict__ mid,
                          int nsrc) {
  const int i = blockIdx.x;
  const int tid = threadIdx.x;
  const int chunk = nsrc >> 6;
  double s = 0.0;
  const float* p = part + (size_t)i * chunk * 2 * C + tid;
  for (int k = 0; k < chunk; ++k) s += (double)p[(size_t)k * 2 * C];
  mid[i * 2 * C + tid] = (float)s;
}

template <int C>
__global__ void reduce_stats_t(const float* __restrict__ part, int nblk,
                               const float* __restrict__ gamma,
                               const float* __restrict__ beta, float cnt,
                               float* __restrict__ scale, float* __restrict__ shift) {
  __shared__ double redS[8 * C];
  __shared__ double redQ[8 * C];
  const int tid = threadIdx.x;
  const int c = tid % C;
  const int sub = tid / C;
  double s = 0.0, q = 0.0;
  for (int i = sub; i < nblk; i += 8) {
    s += (double)part[i * 2 * C + c];
    q += (double)part[i * 2 * C + C + c];
  }
  redS[sub * C + c] = s;
  redQ[sub * C + c] = q;
  __syncthreads();
  if (tid < C) {
    double ss = 0.0, qq = 0.0;
#pragma unroll
    for (int k = 0; k < 8; ++k) { ss += redS[k * C + tid]; qq += redQ[k * C + tid]; }
    double mean = ss / (double)cnt;
    double var = qq / (double)cnt - mean * mean;
    float inv = 1.0f / sqrtf((float)var + 1e-5f);
    float sc = gamma[tid] * inv;
    scale[tid] = sc;
    shift[tid] = fmaf(-(float)mean, sc, beta[tid]);
  }
}

// ------------------------------------------------- K3: layer2 GEMM ----------
template <bool STOREH2E>
__global__ __launch_bounds__(256) void k3_mm2(const float* __restrict__ Q,
                                              const float* __restrict__ R,
                                              const int* __restrict__ idx,
                                              const float* __restrict__ w2,
                                              const float* __restrict__ b2,
                                              const float* __restrict__ stats,
                                              __half* __restrict__ h2e,
                                              float* __restrict__ part2,
                                              const float* __restrict__ xyz,
                                              float* __restrict__ fdist,
                                              int* __restrict__ fpsb) {
  __shared__ float sE[64 * 132];
  const int tid = threadIdx.x;
  if (blockIdx.x < 8) {
    fps_chunk(xyz, fdist, fpsb, sE, (int*)(sE + 8), blockIdx.x, 501, 801, tid);
    return;
  }
  const int blk = blockIdx.x - 8;
  const int b = blk >> 10;
  const int n0 = (blk & 1023) * 4;
  const int rowbase = blk * 64;
  const float* scale1 = stats;
  const float* shift1 = stats + 128;
  {
    const int r = tid >> 2, c0 = (tid & 3) * 32;
    const int np2 = r >> 4, k = r & 15;
    const int n = n0 + np2;
    const int m = idx[(b * NN + n) * KNb + k];
    const float4* qp = (const float4*)(Q + (size_t)(b * NN + n) * CO + c0);
    const float4* rp = (const float4*)(R + (size_t)(b * NN + m) * CO + c0);
    const float4* s4p = (const float4*)(scale1 + c0);
    const float4* h4p = (const float4*)(shift1 + c0);
    float* se = sE + r * 132 + c0;
#pragma unroll
    for (int j = 0; j < 8; ++j) {
      float4 a = qp[j];
      float4 bb = rp[j];
      float4 v = make_float4(a.x + bb.x, a.y + bb.y, a.z + bb.z, a.w + bb.w);
      ((float4*)se)[j] = bnrelu4(v, s4p[j], h4p[j]);
    }
  }
  __syncthreads();
  const int g = tid & 15;
  const int col0 = (tid >> 4) * 8;
  float acc[4][8];
#pragma unroll
  for (int i = 0; i < 4; ++i)
#pragma unroll
    for (int j = 0; j < 8; ++j) acc[i][j] = 0.f;
#pragma unroll 2
  for (int c = 0; c < CO; ++c) {
    float ev[4];
    ev[0] = sE[g * 132 + c];
    ev[1] = sE[(g + 16) * 132 + c];
    ev[2] = sE[(g + 32) * 132 + c];
    ev[3] = sE[(g + 48) * 132 + c];
    const float4 wa = *(const float4*)(w2 + c * CO + col0);
    const float4 wb = *(const float4*)(w2 + c * CO + col0 + 4);
    const float wv[8] = {wa.x, wa.y, wa.z, wa.w, wb.x, wb.y, wb.z, wb.w};
#pragma unroll
    for (int i = 0; i < 4; ++i)
#pragma unroll
      for (int j = 0; j < 8; ++j) acc[i][j] = fmaf(ev[i], wv[j], acc[i][j]);
  }
  const float4 bA = *(const float4*)(b2 + col0);
  const float4 bB = *(const float4*)(b2 + col0 + 4);
  const float bv[8] = {bA.x, bA.y, bA.z, bA.w, bB.x, bB.y, bB.z, bB.w};
  float bsum[8], bsq[8];
#pragma unroll
  for (int j = 0; j < 8; ++j) { bsum[j] = 0.f; bsq[j] = 0.f; }
#pragma unroll
  for (int i = 0; i < 4; ++i) {
    float v[8];
#pragma unroll
    for (int j = 0; j < 8; ++j) {
      v[j] = acc[i][j] + bv[j];
      bsum[j] += v[j];
      bsq[j] = fmaf(v[j], v[j], bsq[j]);
    }
    if constexpr (STOREH2E) {
      __half2 pk[4];
      pk[0] = __floats2half2_rn(v[0], v[1]);
      pk[1] = __floats2half2_rn(v[2], v[3]);
      pk[2] = __floats2half2_rn(v[4], v[5]);
      pk[3] = __floats2half2_rn(v[6], v[7]);
      *(float4*)(h2e + (size_t)(rowbase + g + 16 * i) * CO + col0) = *(float4*)pk;
    }
  }
  __syncthreads();
  float* sS = sE;
  float* sQ2 = sE + 2048;
#pragma unroll
  for (int j = 0; j < 8; ++j) {
    sS[g * 128 + col0 + j] = bsum[j];
    sQ2[g * 128 + col0 + j] = bsq[j];
  }
  __syncthreads();
  if (tid < 128) {
    float ss = 0.f, qq = 0.f;
#pragma unroll
    for (int gg = 0; gg < 16; ++gg) {
      ss += sS[gg * 128 + tid];
      qq += sQ2[gg * 128 + tid];
    }
    part2[blk * 256 + tid] = ss;
    part2[blk * 256 + 128 + tid] = qq;
  }
}

// ------------------------------------------------- e2 tile builder ----------
template <bool RECOMP>
__device__ __forceinline__ void build_e2_tile(
    float* sE, const int b, const int n0, const int rowbase, const int tid,
    const float* __restrict__ Q, const float* __restrict__ R,
    const int* __restrict__ idx, const float* __restrict__ w2,
    const float* __restrict__ b2, const __half* __restrict__ h2e,
    const float* __restrict__ stats) {
  const float* sc2 = stats + 256;
  const float* sh2 = stats + 384;
  const int r = tid >> 2, c0 = (tid & 3) * 32;
  if constexpr (!RECOMP) {
    const __half* hp = h2e + (size_t)(rowbase + r) * CO + c0;
    const float4* s4p = (const float4*)(sc2 + c0);
    const float4* h4p = (const float4*)(sh2 + c0);
    float* se = sE + r * 132 + c0;
#pragma unroll
    for (int jj = 0; jj < 4; ++jj) {
      float4 raw = *(const float4*)(hp + jj * 8);
      const __half2* hh = (const __half2*)&raw;
      float2 f0 = __half22float2(hh[0]);
      float2 f1 = __half22float2(hh[1]);
      float2 f2 = __half22float2(hh[2]);
      float2 f3 = __half22float2(hh[3]);
      float4 v0 = make_float4(f0.x, f0.y, f1.x, f1.y);
      float4 v1 = make_float4(f2.x, f2.y, f3.x, f3.y);
      ((float4*)se)[2 * jj] = bnrelu4(v0, s4p[2 * jj], h4p[2 * jj]);
      ((float4*)se)[2 * jj + 1] = bnrelu4(v1, s4p[2 * jj + 1], h4p[2 * jj + 1]);
    }
    __syncthreads();
  } else {
    const float* sc1 = stats;
    const float* sh1 = stats + 128;
    {
      const int np2 = r >> 4, k = r & 15;
      const int n = n0 + np2;
      const int m = idx[(b * NN + n) * KNb + k];
      const float4* qp = (const float4*)(Q + (size_t)(b * NN + n) * CO + c0);
      const float4* rp = (const float4*)(R + (size_t)(b * NN + m) * CO + c0);
      const float4* s4p = (const float4*)(sc1 + c0);
      const float4* h4p = (const float4*)(sh1 + c0);
      float* se = sE + r * 132 + c0;
#pragma unroll
      for (int j = 0; j < 8; ++j) {
        float4 a = qp[j];
        float4 bb = rp[j];
        float4 v = make_float4(a.x + bb.x, a.y + bb.y, a.z + bb.z, a.w + bb.w);
        ((float4*)se)[j] = bnrelu4(v, s4p[j], h4p[j]);
      }
    }
    __syncthreads();
    const int g = tid & 15, col0 = (tid >> 4) * 8;
    float acc[4][8];
#pragma unroll
    for (int i = 0; i < 4; ++i)
#pragma unroll
      for (int j = 0; j < 8; ++j) acc[i][j] = 0.f;
#pragma unroll 2
    for (int c = 0; c < CO; ++c) {
      float ev[4];
      ev[0] = sE[g * 132 + c];
      ev[1] = sE[(g + 16) * 132 + c];
      ev[2] = sE[(g + 32) * 132 + c];
      ev[3] = sE[(g + 48) * 132 + c];
      const float4 wa = *(const float4*)(w2 + c * CO + col0);
      const float4 wb = *(const float4*)(w2 + c * CO + col0 + 4);
      const float wv[8] = {wa.x, wa.y, wa.z, wa.w, wb.x, wb.y, wb.z, wb.w};
#pragma unroll
      for (int i = 0; i < 4; ++i)
#pragma unroll
        for (int j = 0; j < 8; ++j) acc[i][j] = fmaf(ev[i], wv[j], acc[i][j]);
    }
    __syncthreads();  // all reads of e1 done before overwrite
    const float4 bA = *(const float4*)(b2 + col0);
    const float4 bB = *(const float4*)(b2 + col0 + 4);
    const float4 sA4 = *(const float4*)(sc2 + col0);
    const float4 sB4 = *(const float4*)(sc2 + col0 + 4);
    const float4 hA4 = *(const float4*)(sh2 + col0);
    const float4 hB4 = *(const float4*)(sh2 + col0 + 4);
#pragma unroll
    for (int i = 0; i < 4; ++i) {
      float4 v0 = make_float4(acc[i][0] + bA.x, acc[i][1] + bA.y,
                              acc[i][2] + bA.z, acc[i][3] + bA.w);
      float4 v1 = make_float4(acc[i][4] + bB.x, acc[i][5] + bB.y,
                              acc[i][6] + bB.z, acc[i][7] + bB.w);
      float* se = sE + (g + 16 * i) * 132 + col0;
      *(float4*)se = bnrelu4(v0, sA4, hA4);
      *(float4*)(se + 4) = bnrelu4(v1, sB4, hB4);
    }
    __syncthreads();
  }
}

// ------------------------------------------------- K4: attention MLP1 -------
template <bool RECOMP>
__global__ __launch_bounds__(256) void k4_attn1(
    const float* __restrict__ Q, const float* __restrict__ R,
    const int* __restrict__ idx, const float* __restrict__ w2,
    const float* __restrict__ b2, const __half* __restrict__ h2e,
    const float* __restrict__ wa1, const float* __restrict__ ba1,
    const float* __restrict__ stats, __half* __restrict__ t,
    float* __restrict__ parta, const float* __restrict__ xyz,
    float* __restrict__ fdist, int* __restrict__ fpsb) {
  __shared__ float sE[64 * 132];
  const int tid = threadIdx.x;
  if (blockIdx.x < 8) {
    fps_chunk(xyz, fdist, fpsb, sE, (int*)(sE + 8), blockIdx.x, 801, 951, tid);
    return;
  }
  const int blk = blockIdx.x - 8;
  const int b = blk >> 10;
  const int n0 = (blk & 1023) * 4;
  const int rowbase = blk * 64;
  build_e2_tile<RECOMP>(sE, b, n0, rowbase, tid, Q, R, idx, w2, b2, h2e, stats);
  // t-GEMM: 1 row/thread, 8 cols (r = tid>>2 in [0,64), q = tid&3)
  const int r = tid >> 2;
  const int q = tid & 3;
  float acc[8];
#pragma unroll
  for (int j = 0; j < 8; ++j) acc[j] = 0.f;
#pragma unroll 4
  for (int c = 0; c < CO; ++c) {
    float e = sE[r * 132 + c];
    const float4 wA = *(const float4*)(wa1 + c * 32 + q * 8);
    const float4 wB = *(const float4*)(wa1 + c * 32 + q * 8 + 4);
    acc[0] = fmaf(e, wA.x, acc[0]);
    acc[1] = fmaf(e, wA.y, acc[1]);
    acc[2] = fmaf(e, wA.z, acc[2]);
    acc[3] = fmaf(e, wA.w, acc[3]);
    acc[4] = fmaf(e, wB.x, acc[4]);
    acc[5] = fmaf(e, wB.y, acc[5]);
    acc[6] = fmaf(e, wB.z, acc[6]);
    acc[7] = fmaf(e, wB.w, acc[7]);
  }
  const float4 bA = *(const float4*)(ba1 + q * 8);
  const float4 bB = *(const float4*)(ba1 + q * 8 + 4);
  float tv[8] = {acc[0] + bA.x, acc[1] + bA.y, acc[2] + bA.z, acc[3] + bA.w,
                 acc[4] + bB.x, acc[5] + bB.y, acc[6] + bB.z, acc[7] + bB.w};
  {
    __half2 pk[4];
    pk[0] = __floats2half2_rn(tv[0], tv[1]);
    pk[1] = __floats2half2_rn(tv[2], tv[3]);
    pk[2] = __floats2half2_rn(tv[4], tv[5]);
    pk[3] = __floats2half2_rn(tv[6], tv[7]);
    *(float4*)(t + (size_t)(rowbase + r) * 32 + q * 8) = *(float4*)pk;
  }
  __syncthreads();  // all sE reads done; reuse as stats scratch
  float* sS = sE;             // [64][33]
  float* sQ = sE + 2176;      // [64][33]
#pragma unroll
  for (int j = 0; j < 8; ++j) {
    sS[r * 33 + q * 8 + j] = tv[j];
    sQ[r * 33 + q * 8 + j] = tv[j] * tv[j];
  }
  __syncthreads();
  if (tid < 32) {
    float ss = 0.f, qq = 0.f;
    for (int rr = 0; rr < 64; ++rr) {
      ss += sS[rr * 33 + tid];
      qq += sQ[rr * 33 + tid];
    }
    parta[blk * 64 + tid] = ss;
    parta[blk * 64 + 32 + tid] = qq;
  }
}

// ------------------------------------------------- K5: softmax + out --------
template <bool RECOMP>
__global__ __launch_bounds__(256) void k5_out(
    const float* __restrict__ Q, const float* __restrict__ R,
    const int* __restrict__ idx, const float* __restrict__ w2,
    const float* __restrict__ b2, const __half* __restrict__ h2e,
    const __half* __restrict__ t, const float* __restrict__ wa2,
    const float* __restrict__ ba2, const float* __restrict__ stats,
    float* __restrict__ out, const float* __restrict__ xyz,
    float* __restrict__ fdist, int* __restrict__ fpsb) {
  __shared__ float sE[64 * 132];
  __shared__ float sA[64];
  const int tid = threadIdx.x;
  if (blockIdx.x < 8) {
    fps_chunk(xyz, fdist, fpsb, sE, (int*)(sE + 8), blockIdx.x, 951, 1024, tid);
    return;
  }
  const int blk = blockIdx.x - 8;
  const int b = blk >> 10;
  const int n0 = (blk & 1023) * 4;
  const int rowbase = blk * 64;
  build_e2_tile<RECOMP>(sE, b, n0, rowbase, tid, Q, R, idx, w2, b2, h2e, stats);
  const float* sna = stats + 512;
  const float* sha = stats + 544;
  {
    const int r = tid >> 2, q = tid & 3;
    float a2 = 0.f;
    float4 raw = *(const float4*)(t + (size_t)(rowbase + r) * 32 + q * 8);
    const __half2* hh = (const __half2*)&raw;
    float tj[8];
    float2 f0 = __half22float2(hh[0]); tj[0] = f0.x; tj[1] = f0.y;
    float2 f1 = __half22float2(hh[1]); tj[2] = f1.x; tj[3] = f1.y;
    float2 f2 = __half22float2(hh[2]); tj[4] = f2.x; tj[5] = f2.y;
    float2 f3 = __half22float2(hh[3]); tj[6] = f3.x; tj[7] = f3.y;
#pragma unroll
    for (int j = 0; j < 8; ++j)
      a2 = fmaf(fmaxf(0.f, fmaf(tj[j], sna[q * 8 + j], sha[q * 8 + j])),
                wa2[q * 8 + j], a2);
    a2 += __shfl_xor(a2, 1);
    a2 += __shfl_xor(a2, 2);
    a2 += ba2[0];
    float m = a2;
#pragma unroll
    for (int off = 4; off < 64; off <<= 1) m = fmaxf(m, __shfl_xor(m, off));
    float p = expf(a2 - m);
    float s = p;
#pragma unroll
    for (int off = 4; off < 64; off <<= 1) s += __shfl_xor(s, off);
    if (q == 0) sA[r] = p / s;
  }
  __syncthreads();
  const int np2 = tid >> 6;
  const int cg = tid & 63;
  const int c0 = cg * 2;
  float o0 = 0.f, o1 = 0.f;
#pragma unroll
  for (int k = 0; k < 16; ++k) {
    float aw = sA[np2 * 16 + k];
    o0 = fmaf(aw, sE[(np2 * 16 + k) * 132 + c0], o0);
    o1 = fmaf(aw, sE[(np2 * 16 + k) * 132 + c0 + 1], o1);
  }
  float* op = out + (size_t)(b * NN + n0 + np2) * CO + c0;
  *(float2*)op = make_float2(o0, o1);
}

// ------------------------------------------------- K6: gather stats ---------
__global__ __launch_bounds__(256) void k6_gstats(const float* __restrict__ out,
                                                 const int* __restrict__ fps,
                                                 float* __restrict__ partf) {
  __shared__ float red[512];
  const int blk = blockIdx.x;
  const int tid = threadIdx.x;
  const int c = tid & 127;
  const int half = tid >> 7;
  float s = 0.f, q = 0.f;
  for (int i = 0; i < 128; ++i) {
    int row = blk * 256 + half * 128 + i;
    int b = row >> 10, p = row & 1023;
    int fi = fps[b * NP + p];
    float v = out[(size_t)(b * NN + fi) * CO + c];
    s += v;
    q = fmaf(v, v, q);
  }
  red[tid] = s;
  red[256 + tid] = q;
  __syncthreads();
  if (tid < 128) {
    partf[blk * 256 + tid] = red[tid] + red[tid + 128];
    partf[blk * 256 + 128 + tid] = red[256 + tid] + red[256 + tid + 128];
  }
}

// ------------------------------------------------- K7: final outputs --------
__global__ __launch_bounds__(256) void k7_final(const float* __restrict__ xyz,
                                                const float* __restrict__ out,
                                                const int* __restrict__ fps,
                                                const float* __restrict__ stats,
                                                float* __restrict__ dout) {
  const int gid = blockIdx.x * 256 + threadIdx.x;
  const int NX = BB * 3 * NP;  // 24576
  if (gid < NX) {
    int b = gid / 3072;
    int rem = gid - b * 3072;
    int d = rem >> 10, p = rem & 1023;
    int fi = fps[b * NP + p];
    dout[gid] = xyz[(b * 3 + d) * NN + fi];
  } else {
    int h = gid - NX;
    if (h < BB * CO * NP) {
      int b = h >> 17;
      int c = (h >> 10) & 127;
      int p = h & 1023;
      int fi = fps[b * NP + p];
      float v = out[(size_t)(b * NN + fi) * CO + c];
      dout[gid] = fmaf(v, stats[576 + c], stats[704 + c]);
    }
  }
}

// ---------------------------------------------------------------------------
extern "C" void kernel_launch(void* const* d_in, const int* in_sizes, int n_in,
                              void* d_out, int out_size, void* d_ws, size_t ws_size,
                              hipStream_t stream) {
  const float* xyz = (const float*)d_in[0];
  const float* feat = (const float*)d_in[1];
  const float* w1 = (const float*)d_in[2];
  const float* b1 = (const float*)d_in[3];
  const float* g1 = (const float*)d_in[4];
  const float* be1 = (const float*)d_in[5];
  const float* w2 = (const float*)d_in[6];
  const float* b2 = (const float*)d_in[7];
  const float* g2 = (const float*)d_in[8];
  const float* be2 = (const float*)d_in[9];
  const float* wa1 = (const float*)d_in[10];
  const float* ba1 = (const float*)d_in[11];
  const float* ga = (const float*)d_in[12];
  const float* bea = (const float*)d_in[13];
  const float* wa2 = (const float*)d_in[14];
  const float* ba2 = (const float*)d_in[15];
  const float* gf = (const float*)d_in[16];
  const float* bf = (const float*)d_in[17];
  float* outp = (float*)d_out;

  char* ws = (char*)d_ws;
  size_t off = 0;
  auto alloc = [&](size_t bytes) -> void* {
    void* p = ws + off;
    off = (off + bytes + 255) & ~(size_t)255;
    return p;
  };
  unsigned long long* part = (unsigned long long*)alloc((size_t)BB * NN * 64 * 8);  // 16.8 MB
  int* idx = (int*)alloc((size_t)BB * NN * KNb * 4);
  int* fpsb = (int*)alloc((size_t)BB * NP * 4);
  float* fdist = (float*)alloc((size_t)BB * NN * 4);
  float* Q = (float*)alloc((size_t)BB * NN * CO * 4);
  float* R = (float*)alloc((size_t)BB * NN * CO * 4);
  float* ob = (float*)alloc((size_t)BB * NN * CO * 4);
  float* part1 = (float*)alloc((size_t)512 * 256 * 4);
  float* part2 = (float*)alloc((size_t)8192 * 256 * 4);
  float* parta = (float*)alloc((size_t)8192 * 64 * 4);
  float* partf = (float*)alloc((size_t)32 * 256 * 4);
  float* mid2 = (float*)alloc((size_t)64 * 256 * 4);
  float* mida = (float*)alloc((size_t)64 * 64 * 4);
  float* stats = (float*)alloc((size_t)1024 * 4);
  __half* tb = (__half*)alloc((size_t)BB * NN * KNb * 32 * 2);  // 33.5 MB, always
  const size_t h2e_bytes = (size_t)BB * NN * KNb * CO * 2;      // 134 MB
  const bool has_h2e = (off + h2e_bytes + 256 <= ws_size);
  __half* h2e = has_h2e ? (__half*)alloc(h2e_bytes) : nullptr;

  const float CNT1 = (float)(BB * NN * KNb);
  front_kernel<<<8 + 512 + 512, 256, 0, stream>>>(xyz, feat, w1, b1, part, Q, R, fdist, fpsb);
  k2m_kernel<<<8 + 512, 256, 0, stream>>>(xyz, part, Q, R, idx, part1, fdist, fpsb);
  reduce_stats_t<128><<<1, 1024, 0, stream>>>(part1, 512, g1, be1, CNT1, stats, stats + 128);
  if (has_h2e)
    k3_mm2<true><<<8 + 8192, 256, 0, stream>>>(Q, R, idx, w2, b2, stats, h2e, part2, xyz, fdist, fpsb);
  else
    k3_mm2<false><<<8 + 8192, 256, 0, stream>>>(Q, R, idx, w2, b2, stats, h2e, part2, xyz, fdist, fpsb);
  reduceA_t<128><<<64, 256, 0, stream>>>(part2, mid2, 8192);
  reduce_stats_t<128><<<1, 1024, 0, stream>>>(mid2, 64, g2, be2, CNT1, stats + 256, stats + 384);
  if (has_h2e)
    k4_attn1<false><<<8 + 8192, 256, 0, stream>>>(Q, R, idx, w2, b2, h2e, wa1, ba1, stats, tb, parta, xyz, fdist, fpsb);
  else
    k4_attn1<true><<<8 + 8192, 256, 0, stream>>>(Q, R, idx, w2, b2, h2e, wa1, ba1, stats, tb, parta, xyz, fdist, fpsb);
  reduceA_t<32><<<64, 64, 0, stream>>>(parta, mida, 8192);
  reduce_stats_t<32><<<1, 256, 0, stream>>>(mida, 64, ga, bea, CNT1, stats + 512, stats + 544);
  if (has_h2e)
    k5_out<false><<<8 + 8192, 256, 0, stream>>>(Q, R, idx, w2, b2, h2e, tb, wa2, ba2, stats, ob, xyz, fdist, fpsb);
  else
    k5_out<true><<<8 + 8192, 256, 0, stream>>>(Q, R, idx, w2, b2, h2e, tb, wa2, ba2, stats, ob, xyz, fdist, fpsb);
  k6_gstats<<<32, 256, 0, stream>>>(ob, fpsb, partf);
  reduce_stats_t<128><<<1, 1024, 0, stream>>>(partf, 32, gf, bf, (float)(BB * NP), stats + 576, stats + 704);
  k7_final<<<4192, 256, 0, stream>>>(xyz, ob, fpsb, stats, outp);
}